// Round 10
// baseline (134.641 us; speedup 1.0000x reference)
//
#include <hip/hip_runtime.h>

typedef __attribute__((ext_vector_type(8))) short bh8;   // 8 x bf16 (4 VGPRs)
typedef __attribute__((ext_vector_type(4))) float fx4;   // 16x16 MFMA accumulator

__device__ __forceinline__ unsigned short f2bf(float f) {
    unsigned int u = __float_as_uint(f);
    u += 0x7FFF + ((u >> 16) & 1);          // RNE
    return (unsigned short)(u >> 16);
}

// pack 2 f32 -> 2 bf16 in one u32 (RNE), low = a, high = b
__device__ __forceinline__ unsigned int cvtpk_bf16(float a, float b) {
    unsigned int r;
    asm("v_cvt_pk_bf16_f32 %0, %1, %2" : "=v"(r) : "v"(a), "v"(b));
    return r;
}

__device__ __forceinline__ bh8 pack4(unsigned int a, unsigned int b,
                                     unsigned int c, unsigned int d) {
    union { unsigned int u[4]; bh8 h; } z;
    z.u[0] = a; z.u[1] = b; z.u[2] = c; z.u[3] = d;
    return z.h;
}

// Stage 8 rows x 64 bf16 cols into LDS (linear dest) via global_load_lds width=16.
// Global source chunk is XOR-swizzled by row&7 (rule #21: swizzle source + read).
__device__ __forceinline__ void stage_rows8(const unsigned short* g, long ldg,
                                            unsigned short* lds, int lane) {
    int r8 = lane >> 3;
    int gc = (lane & 7) ^ r8;
    __builtin_amdgcn_global_load_lds(
        (const __attribute__((address_space(1))) void*)(g + (long)r8 * ldg + gc * 8),
        (__attribute__((address_space(3))) void*)lds, 16, 0, 0);
}

// 16x16x32 fragment read from a swizzled [rows][64] tile (VERIFIED in passing gemm128):
// logical k-chunk = kchunk + (lane>>4), stored at chunk^(row&7).
__device__ __forceinline__ bh8 frag_ld(const unsigned short* t, int row, int kchunk, int lane) {
    int ch = (kchunk + (lane >> 4)) ^ (row & 7);
    return *(const bh8*)(t + row * 64 + ch * 8);
}

// ---------------- cast fp32 -> bf16 ----------------
__global__ __launch_bounds__(256) void castbf(const float* __restrict__ x,
                                              unsigned short* __restrict__ y, int n) {
    int i = (blockIdx.x * 256 + threadIdx.x) * 4;
    if (i < n) {
        float4 v = *(const float4*)(x + i);
        ushort4 o = make_ushort4(f2bf(v.x), f2bf(v.y), f2bf(v.z), f2bf(v.w));
        *(ushort4*)(y + i) = o;
    }
}

// ---------------- transpose + cast W[K][N] fp32 -> Wt[N][K] bf16 ----------------
__global__ __launch_bounds__(256) void transW(const float* __restrict__ W,
                                              unsigned short* __restrict__ Wt,
                                              int K, int N) {
    __shared__ float t[32][33];
    const int n0 = blockIdx.x * 32, k0 = blockIdx.y * 32;
    const int tx = threadIdx.x & 31, ty = threadIdx.x >> 5;
    #pragma unroll
    for (int r = ty; r < 32; r += 8)
        t[r][tx] = W[(size_t)(k0 + r) * N + n0 + tx];
    __syncthreads();
    #pragma unroll
    for (int r = ty; r < 32; r += 8)
        Wt[(size_t)(n0 + r) * K + k0 + tx] = f2bf(t[tx][r]);
}

// ---------------- extract V from qkv, transpose AND kappa-permute: vt[h][d][pos(s)] ----------------
// pos(32a+16b+4g+r) = 32a+8g+4b+r  -- makes the PV A-fragment (single b128 at chunk 4ks+g)
// deliver exactly the kv labeling kv(ks,g,j)=32ks+16(j>>2)+4g+(j&3) that the lane-resident
// P pack (rounds 5/7/8/9 HW-verified) expects. Pure store-index change, free.
__global__ __launch_bounds__(256) void transV(const unsigned short* __restrict__ qkv,
                                              unsigned short* __restrict__ vt) {
    __shared__ unsigned short t[64][65];
    const int s0 = blockIdx.x * 64, h = blockIdx.y;
    const int tx = threadIdx.x & 63, ty = threadIdx.x >> 6;
    #pragma unroll
    for (int r = ty; r < 64; r += 4)
        t[r][tx] = qkv[(size_t)(s0 + r) * 2304 + 1536 + h * 64 + tx];
    __syncthreads();
    const int px = (tx & 32) + ((tx & 16) >> 2) + ((tx & 12) << 1) + (tx & 3);
    #pragma unroll
    for (int r = ty; r < 64; r += 4)
        vt[((size_t)h * 64 + r) * 4096 + s0 + px] = t[tx][r];
}

// ---------------- GEMM 128x128: C[M][N] = A[M][K] * Bt[N][K]^T + bias ----------------
// SCALE_Q: multiply columns [0,768) by log2(e)/8 at store (pre-scales Q for the
// shift-0 exp2 softmax in attn_fwd).
template <int OUT_BF16, int SCALE_Q>
__global__ __launch_bounds__(256) void gemm128(const unsigned short* __restrict__ A,
                                               const unsigned short* __restrict__ Bt,
                                               const float* __restrict__ bias,
                                               void* __restrict__ Cout,
                                               int M, int N, int K) {
    __shared__ __align__(16) unsigned short Ash[128 * 64];
    __shared__ __align__(16) unsigned short Bsh[128 * 64];
    const int m0 = blockIdx.y * 128, n0 = blockIdx.x * 128;
    const int tid = threadIdx.x, wid = tid >> 6, lane = tid & 63;
    const int wr = (wid >> 1) * 64, wc = (wid & 1) * 64;

    fx4 acc[4][4];
    #pragma unroll
    for (int i = 0; i < 4; ++i)
        #pragma unroll
        for (int j = 0; j < 4; ++j)
            acc[i][j] = (fx4){0.f, 0.f, 0.f, 0.f};

    for (int k0 = 0; k0 < K; k0 += 64) {
        #pragma unroll
        for (int g = 0; g < 4; ++g) {
            int rt = (wid * 4 + g) * 8;
            stage_rows8(A + (size_t)(m0 + rt) * K + k0, K, Ash + rt * 64, lane);
            stage_rows8(Bt + (size_t)(n0 + rt) * K + k0, K, Bsh + rt * 64, lane);
        }
        __syncthreads();
        #pragma unroll
        for (int ks = 0; ks < 2; ++ks) {
            bh8 af[4], bfr[4];
            #pragma unroll
            for (int i = 0; i < 4; ++i) af[i] = frag_ld(Ash, wr + i * 16 + (lane & 15), ks * 4, lane);
            #pragma unroll
            for (int j = 0; j < 4; ++j) bfr[j] = frag_ld(Bsh, wc + j * 16 + (lane & 15), ks * 4, lane);
            #pragma unroll
            for (int i = 0; i < 4; ++i)
                #pragma unroll
                for (int j = 0; j < 4; ++j)
                    acc[i][j] = __builtin_amdgcn_mfma_f32_16x16x32_bf16(af[i], bfr[j], acc[i][j], 0, 0, 0);
        }
        __syncthreads();
    }

    const int cc = lane & 15, g4 = (lane >> 4) * 4;
    #pragma unroll
    for (int j = 0; j < 4; ++j) {
        int col = n0 + wc + j * 16 + cc;
        float bv = bias[col];
        float sc = (SCALE_Q && col < 768) ? 0.18033688011112042f : 1.0f;
        #pragma unroll
        for (int i = 0; i < 4; ++i) {
            #pragma unroll
            for (int r = 0; r < 4; ++r) {
                int row = m0 + wr + i * 16 + g4 + r;
                float v = (acc[i][j][r] + bv) * sc;
                if (OUT_BF16)
                    ((unsigned short*)Cout)[(size_t)row * N + col] = f2bf(v);
                else
                    ((float*)Cout)[(size_t)row * N + col] = v;
            }
        }
    }
}

// ---------------- GEMM 64x64 (for small-N output projection; 768 blocks = 3/CU) ----------------
__global__ __launch_bounds__(256) void gemm64(const unsigned short* __restrict__ A,
                                              const unsigned short* __restrict__ Bt,
                                              const float* __restrict__ bias,
                                              float* __restrict__ Cout,
                                              int M, int N, int K) {
    __shared__ __align__(16) unsigned short Ash[64 * 64];
    __shared__ __align__(16) unsigned short Bsh[64 * 64];
    const int m0 = blockIdx.y * 64, n0 = blockIdx.x * 64;
    const int tid = threadIdx.x, wid = tid >> 6, lane = tid & 63;
    const int wr = (wid >> 1) * 32, wc = (wid & 1) * 32;

    fx4 acc[2][2];
    #pragma unroll
    for (int i = 0; i < 2; ++i)
        #pragma unroll
        for (int j = 0; j < 2; ++j)
            acc[i][j] = (fx4){0.f, 0.f, 0.f, 0.f};

    for (int k0 = 0; k0 < K; k0 += 64) {
        #pragma unroll
        for (int g = 0; g < 2; ++g) {
            int rt = (wid * 2 + g) * 8;
            stage_rows8(A + (size_t)(m0 + rt) * K + k0, K, Ash + rt * 64, lane);
            stage_rows8(Bt + (size_t)(n0 + rt) * K + k0, K, Bsh + rt * 64, lane);
        }
        __syncthreads();
        #pragma unroll
        for (int ks = 0; ks < 2; ++ks) {
            bh8 af[2], bfr[2];
            #pragma unroll
            for (int i = 0; i < 2; ++i) af[i] = frag_ld(Ash, wr + i * 16 + (lane & 15), ks * 4, lane);
            #pragma unroll
            for (int j = 0; j < 2; ++j) bfr[j] = frag_ld(Bsh, wc + j * 16 + (lane & 15), ks * 4, lane);
            #pragma unroll
            for (int i = 0; i < 2; ++i)
                #pragma unroll
                for (int j = 0; j < 2; ++j)
                    acc[i][j] = __builtin_amdgcn_mfma_f32_16x16x32_bf16(af[i], bfr[j], acc[i][j], 0, 0, 0);
        }
        __syncthreads();
    }

    const int cc = lane & 15, g4 = (lane >> 4) * 4;
    #pragma unroll
    for (int j = 0; j < 2; ++j) {
        int col = n0 + wc + j * 16 + cc;
        float bv = bias[col];
        #pragma unroll
        for (int i = 0; i < 2; ++i) {
            #pragma unroll
            for (int r = 0; r < 4; ++r) {
                int row = m0 + wr + i * 16 + g4 + r;
                Cout[(size_t)row * N + col] = acc[i][j][r] + bv;
            }
        }
    }
}

// ---------------- flash attention: 2x2 wave split, shift-0 softmax, l via ones-MFMA ----------------
// grid (S/64, H); block = 4 waves. Wave (wq,wk) = (wid>>1, wid&1) owns q-rows
// [q0+32wq, +32) x kv-rows [32wk, +32) of each staged tile. Q in registers.
// l = sum_kv P computed by an extra MFMA with a constant all-ones A-operand: every
// output reg of that MFMA equals l[q] (rows of ones), so no broadcast or VALU adds.
// Accumulator zero-init flows through the MFMA C-operand (persistent z0 quad).
// Epilogue: deterministic 2-way cross-wave O/l reduction through an LDS overlay.
__global__ __launch_bounds__(256) void attn_fwd(const unsigned short* __restrict__ qkv,
                                                const unsigned short* __restrict__ vt,
                                                unsigned short* __restrict__ ao) {
    __shared__ __align__(16) char smem[40960];
    unsigned short* Qs  = (unsigned short*)smem;              // [64*64] 8 KB
    unsigned short* Ks0 = (unsigned short*)(smem + 8192);
    unsigned short* Ks1 = (unsigned short*)(smem + 16384);
    unsigned short* Vs0 = (unsigned short*)(smem + 24576);
    unsigned short* Vs1 = (unsigned short*)(smem + 32768);
    float* Of    = (float*)smem;            // epilogue overlay: [64 q][68] f32 = 17408 B
    float* l_lds = (float*)(smem + 17408);  // [64] f32 (overlay dead K/Q buffers)

    const int h = blockIdx.y, q0 = blockIdx.x * 64;
    const int tid = threadIdx.x, wid = tid >> 6, lane = tid & 63;
    const int g = lane >> 4, qc = lane & 15, x = qc & 7;
    const int wq = wid >> 1, wk = wid & 1;

    const unsigned short* qg_ = qkv + (size_t)q0 * 2304 + h * 64;
    const unsigned short* kgb = qkv + 768 + h * 64;
    const unsigned short* vgb = vt + (size_t)h * 64 * 4096;

    // stage Q tile + KV tile 0 (block-wide, same pattern as verified rounds)
    #pragma unroll
    for (int gg = 0; gg < 2; ++gg) {
        int rt = (wid * 2 + gg) * 8;
        stage_rows8(qg_ + (size_t)rt * 2304, 2304, Qs + rt * 64, lane);
        stage_rows8(kgb + (size_t)rt * 2304, 2304, Ks0 + rt * 64, lane);
        stage_rows8(vgb + (size_t)rt * 4096, 4096, Vs0 + rt * 64, lane);
    }
    __syncthreads();

    // Q fragments for this wave's q-half (2 q-groups x 2 k-chunks), in registers for good
    bh8 qf[2][2];
    #pragma unroll
    for (int qg = 0; qg < 2; ++qg)
        #pragma unroll
        for (int kc = 0; kc < 2; ++kc)
            qf[qg][kc] = frag_ld(Qs, 32 * wq + 16 * qg + qc, 4 * kc, lane);

    // hoisted per-lane LDS short-offsets (constant across the KV loop)
    int koff[2][2], voff[4];
    #pragma unroll
    for (int jm = 0; jm < 2; ++jm)
        #pragma unroll
        for (int kc = 0; kc < 2; ++kc)
            koff[jm][kc] = (32 * wk + 16 * jm + qc) * 64 + ((4 * kc + g) ^ x) * 8;
    #pragma unroll
    for (int dj = 0; dj < 4; ++dj)
        voff[dj] = (16 * dj + qc) * 64 + ((4 * wk + g) ^ x) * 8;

    const fx4 z0 = (fx4){0.f, 0.f, 0.f, 0.f};
    const bh8 ones8 = pack4(0x3F803F80u, 0x3F803F80u, 0x3F803F80u, 0x3F803F80u);

    fx4 oacP[4][2];   // [dj][qg], kv-partial O^T
    fx4 oacL[2];      // [qg], every reg = partial l[q]
    #pragma unroll
    for (int qg = 0; qg < 2; ++qg) {
        oacL[qg] = z0;
        #pragma unroll
        for (int dj = 0; dj < 4; ++dj) oacP[dj][qg] = z0;
    }

    const unsigned short* knext = kgb + (size_t)64 * 2304;
    const unsigned short* vnext = vgb + 64;

    auto tile_step = [&](const unsigned short* Kc, const unsigned short* Vc,
                         unsigned short* Kd, unsigned short* Vd, bool pref) {
        if (pref) {  // prefetch next KV tile (drained at the loop-end barrier)
            #pragma unroll
            for (int gg = 0; gg < 2; ++gg) {
                int rt = (wid * 2 + gg) * 8;
                stage_rows8(knext + (size_t)rt * 2304, 2304, Kd + rt * 64, lane);
                stage_rows8(vnext + (size_t)rt * 4096, 4096, Vd + rt * 64, lane);
            }
            knext += (size_t)64 * 2304;
            vnext += 64;
        }

        // S^T = K . Q^T over this wave's kv-half (zero-init through the C operand)
        bh8 kf[2][2];
        #pragma unroll
        for (int jm = 0; jm < 2; ++jm) {
            kf[jm][0] = *(const bh8*)(Kc + koff[jm][0]);
            kf[jm][1] = *(const bh8*)(Kc + koff[jm][1]);
        }
        fx4 sT[2][2];
        __builtin_amdgcn_s_setprio(1);
        #pragma unroll
        for (int jm = 0; jm < 2; ++jm)
            #pragma unroll
            for (int qg = 0; qg < 2; ++qg) {
                fx4 z = __builtin_amdgcn_mfma_f32_16x16x32_bf16(kf[jm][0], qf[qg][0], z0, 0, 0, 0);
                sT[jm][qg] = __builtin_amdgcn_mfma_f32_16x16x32_bf16(kf[jm][1], qf[qg][1], z, 0, 0, 0);
            }
        __builtin_amdgcn_s_setprio(0);

        // P = exp2(S^T) (Q pre-scaled by log2(e)/8; shift-0 safe, rounds 8/9 verified)
        #pragma unroll
        for (int jm = 0; jm < 2; ++jm)
            #pragma unroll
            for (int qg = 0; qg < 2; ++qg) {
                sT[jm][qg][0] = __builtin_amdgcn_exp2f(sT[jm][qg][0]);
                sT[jm][qg][1] = __builtin_amdgcn_exp2f(sT[jm][qg][1]);
                sT[jm][qg][2] = __builtin_amdgcn_exp2f(sT[jm][qg][2]);
                sT[jm][qg][3] = __builtin_amdgcn_exp2f(sT[jm][qg][3]);
            }

        // O^T += V^T . P over kv-half (ks = wk); l += ones . P (extra MFMA, no VALU)
        bh8 vf[4];
        #pragma unroll
        for (int dj = 0; dj < 4; ++dj) vf[dj] = *(const bh8*)(Vc + voff[dj]);
        __builtin_amdgcn_s_setprio(1);
        #pragma unroll
        for (int qg = 0; qg < 2; ++qg) {
            bh8 pb = pack4(cvtpk_bf16(sT[0][qg][0], sT[0][qg][1]),
                           cvtpk_bf16(sT[0][qg][2], sT[0][qg][3]),
                           cvtpk_bf16(sT[1][qg][0], sT[1][qg][1]),
                           cvtpk_bf16(sT[1][qg][2], sT[1][qg][3]));
            #pragma unroll
            for (int dj = 0; dj < 4; ++dj)
                oacP[dj][qg] = __builtin_amdgcn_mfma_f32_16x16x32_bf16(vf[dj], pb, oacP[dj][qg], 0, 0, 0);
            oacL[qg] = __builtin_amdgcn_mfma_f32_16x16x32_bf16(ones8, pb, oacL[qg], 0, 0, 0);
        }
        __builtin_amdgcn_s_setprio(0);
        __syncthreads();  // one barrier/tile: drains prefetch + protects buffer swap
    };

    for (int t2 = 0; t2 < 32; ++t2) {
        tile_step(Ks0, Vs0, Ks1, Vs1, true);
        tile_step(Ks1, Vs1, Ks0, Vs0, t2 < 31);
    }

    // ---- epilogue: 2-way cross-wave (wk) reduction, then scale + store ----
    // wk==1 waves publish partials into the LDS overlay (K/Q buffers are dead here)
    if (wk == 1) {
        #pragma unroll
        for (int qg = 0; qg < 2; ++qg) {
            int q = 32 * wq + 16 * qg + qc;
            #pragma unroll
            for (int dj = 0; dj < 4; ++dj)
                *(fx4*)(Of + q * 68 + 16 * dj + 4 * g) = oacP[dj][qg];
            l_lds[q] = oacL[qg][0];   // all 4 g-lanes hold/write the same value
        }
    }
    __syncthreads();
    if (wk == 0) {
        #pragma unroll
        for (int qg = 0; qg < 2; ++qg) {
            int q = 32 * wq + 16 * qg + qc;
            float inv = 1.0f / (oacL[qg][0] + l_lds[q]);
            unsigned short* aop = ao + (size_t)(q0 + q) * 768 + h * 64;
            #pragma unroll
            for (int dj = 0; dj < 4; ++dj) {
                fx4 o = oacP[dj][qg];
                fx4 p = *(const fx4*)(Of + q * 68 + 16 * dj + 4 * g);
                int d0 = dj * 16 + 4 * g;
                *(unsigned int*)(aop + d0)     = cvtpk_bf16((o[0] + p[0]) * inv, (o[1] + p[1]) * inv);
                *(unsigned int*)(aop + d0 + 2) = cvtpk_bf16((o[2] + p[2]) * inv, (o[3] + p[3]) * inv);
            }
        }
    }
}

extern "C" void kernel_launch(void* const* d_in, const int* in_sizes, int n_in,
                              void* d_out, int out_size, void* d_ws, size_t ws_size,
                              hipStream_t stream) {
    const float* x     = (const float*)d_in[0];   // [4096,768]
    const float* w_qkv = (const float*)d_in[1];   // [768,2304]
    const float* b_qkv = (const float*)d_in[2];   // [2304]
    const float* w_out = (const float*)d_in[3];   // [768,768]
    const float* b_out = (const float*)d_in[4];   // [768]
    float* out = (float*)d_out;                   // [4096,768] fp32

    const int S = 4096, E = 768, E3 = 2304, H = 12;

    unsigned short* xb    = (unsigned short*)d_ws;          // S*E
    unsigned short* wqkvT = xb    + (size_t)S * E;          // E3*E
    unsigned short* woutT = wqkvT + (size_t)E3 * E;         // E*E
    unsigned short* qkvb  = woutT + (size_t)E * E;          // S*E3
    unsigned short* vtp   = qkvb  + (size_t)S * E3;         // H*64*S
    unsigned short* ao    = vtp   + (size_t)H * 64 * S;     // S*E

    castbf<<<dim3((S * E) / (256 * 4)), 256, 0, stream>>>(x, xb, S * E);
    transW<<<dim3(E3 / 32, E / 32), 256, 0, stream>>>(w_qkv, wqkvT, E, E3);
    transW<<<dim3(E / 32, E / 32), 256, 0, stream>>>(w_out, woutT, E, E);
    gemm128<1, 1><<<dim3(E3 / 128, S / 128), 256, 0, stream>>>(xb, wqkvT, b_qkv, qkvb, S, E3, E);
    transV<<<dim3(S / 64, H), 256, 0, stream>>>(qkvb, vtp);
    attn_fwd<<<dim3(S / 64, H), 256, 0, stream>>>(qkvb, vtp, ao);
    gemm64<<<dim3(E / 64, S / 64), 256, 0, stream>>>(ao, woutT, b_out, out, S, E, E);
}

// Round 11
// 124.683 us; speedup vs baseline: 1.0799x; 1.0799x over previous
//
#include <hip/hip_runtime.h>

typedef __attribute__((ext_vector_type(8))) short bh8;   // 8 x bf16 (4 VGPRs)
typedef __attribute__((ext_vector_type(4))) float fx4;   // 16x16 MFMA accumulator

__device__ __forceinline__ unsigned short f2bf(float f) {
    unsigned int u = __float_as_uint(f);
    u += 0x7FFF + ((u >> 16) & 1);          // RNE
    return (unsigned short)(u >> 16);
}

// pack 2 f32 -> 2 bf16 in one u32 (RNE), low = a, high = b
__device__ __forceinline__ unsigned int cvtpk_bf16(float a, float b) {
    unsigned int r;
    asm("v_cvt_pk_bf16_f32 %0, %1, %2" : "=v"(r) : "v"(a), "v"(b));
    return r;
}

__device__ __forceinline__ bh8 pack4(unsigned int a, unsigned int b,
                                     unsigned int c, unsigned int d) {
    union { unsigned int u[4]; bh8 h; } z;
    z.u[0] = a; z.u[1] = b; z.u[2] = c; z.u[3] = d;
    return z.h;
}

// Stage 8 rows x 64 bf16 cols into LDS (linear dest) via global_load_lds width=16.
// Global source chunk is XOR-swizzled by row&7 (rule #21: swizzle source + read).
__device__ __forceinline__ void stage_rows8(const unsigned short* g, long ldg,
                                            unsigned short* lds, int lane) {
    int r8 = lane >> 3;
    int gc = (lane & 7) ^ r8;
    __builtin_amdgcn_global_load_lds(
        (const __attribute__((address_space(1))) void*)(g + (long)r8 * ldg + gc * 8),
        (__attribute__((address_space(3))) void*)lds, 16, 0, 0);
}

// 16x16x32 fragment read from a swizzled [rows][64] tile (VERIFIED in passing gemm128):
// logical k-chunk = kchunk + (lane>>4), stored at chunk^(row&7).
__device__ __forceinline__ bh8 frag_ld(const unsigned short* t, int row, int kchunk, int lane) {
    int ch = (kchunk + (lane >> 4)) ^ (row & 7);
    return *(const bh8*)(t + row * 64 + ch * 8);
}

// ---------------- cast fp32 -> bf16 ----------------
__global__ __launch_bounds__(256) void castbf(const float* __restrict__ x,
                                              unsigned short* __restrict__ y, int n) {
    int i = (blockIdx.x * 256 + threadIdx.x) * 4;
    if (i < n) {
        float4 v = *(const float4*)(x + i);
        ushort4 o = make_ushort4(f2bf(v.x), f2bf(v.y), f2bf(v.z), f2bf(v.w));
        *(ushort4*)(y + i) = o;
    }
}

// ---------------- transpose + cast W[K][N] fp32 -> Wt[N][K] bf16 ----------------
__global__ __launch_bounds__(256) void transW(const float* __restrict__ W,
                                              unsigned short* __restrict__ Wt,
                                              int K, int N) {
    __shared__ float t[32][33];
    const int n0 = blockIdx.x * 32, k0 = blockIdx.y * 32;
    const int tx = threadIdx.x & 31, ty = threadIdx.x >> 5;
    #pragma unroll
    for (int r = ty; r < 32; r += 8)
        t[r][tx] = W[(size_t)(k0 + r) * N + n0 + tx];
    __syncthreads();
    #pragma unroll
    for (int r = ty; r < 32; r += 8)
        Wt[(size_t)(n0 + r) * K + k0 + tx] = f2bf(t[tx][r]);
}

// ---------------- extract V from qkv, transpose AND kappa-permute: vt[h][d][pos(s)] ----------------
// pos(32a+16b+4g+r) = 32a+8g+4b+r  -- makes the PV A-fragment (single b128 at chunk 4ks+g)
// deliver exactly the kv labeling kv(ks,g,j)=32ks+16(j>>2)+4g+(j&3) that the lane-resident
// P pack (rounds 5/7/8/9 HW-verified) expects. Pure store-index change, free.
__global__ __launch_bounds__(256) void transV(const unsigned short* __restrict__ qkv,
                                              unsigned short* __restrict__ vt) {
    __shared__ unsigned short t[64][65];
    const int s0 = blockIdx.x * 64, h = blockIdx.y;
    const int tx = threadIdx.x & 63, ty = threadIdx.x >> 6;
    #pragma unroll
    for (int r = ty; r < 64; r += 4)
        t[r][tx] = qkv[(size_t)(s0 + r) * 2304 + 1536 + h * 64 + tx];
    __syncthreads();
    const int px = (tx & 32) + ((tx & 16) >> 2) + ((tx & 12) << 1) + (tx & 3);
    #pragma unroll
    for (int r = ty; r < 64; r += 4)
        vt[((size_t)h * 64 + r) * 4096 + s0 + px] = t[tx][r];
}

// ---------------- QKV GEMM, 64x128 tile: C[M][N] = A[M][K] * Bt[N][K]^T + bias ----------------
// BM=64 halves the per-block work vs 128x128: grid = 1152 blocks = 4.5/CU (tail ~11%
// vs ~33% at 576 blocks), LDS 24.5 KB (more co-resident blocks overlap the barriers).
// Columns [0,768) scaled by log2(e)/8 at store (pre-scales Q for shift-0 exp2 softmax).
__global__ __launch_bounds__(256) void gemm_qkv(const unsigned short* __restrict__ A,
                                                const unsigned short* __restrict__ Bt,
                                                const float* __restrict__ bias,
                                                unsigned short* __restrict__ Cout,
                                                int M, int N, int K) {
    __shared__ __align__(16) unsigned short Ash[64 * 64];
    __shared__ __align__(16) unsigned short Bsh[128 * 64];
    const int m0 = blockIdx.y * 64, n0 = blockIdx.x * 128;
    const int tid = threadIdx.x, wid = tid >> 6, lane = tid & 63;
    const int wr = (wid >> 1) * 32, wc = (wid & 1) * 64;

    fx4 acc[2][4];
    #pragma unroll
    for (int i = 0; i < 2; ++i)
        #pragma unroll
        for (int j = 0; j < 4; ++j)
            acc[i][j] = (fx4){0.f, 0.f, 0.f, 0.f};

    for (int k0 = 0; k0 < K; k0 += 64) {
        #pragma unroll
        for (int g = 0; g < 2; ++g) {
            int rt = (wid * 2 + g) * 8;
            stage_rows8(A + (size_t)(m0 + rt) * K + k0, K, Ash + rt * 64, lane);
        }
        #pragma unroll
        for (int g = 0; g < 4; ++g) {
            int rt = (wid * 4 + g) * 8;
            stage_rows8(Bt + (size_t)(n0 + rt) * K + k0, K, Bsh + rt * 64, lane);
        }
        __syncthreads();
        #pragma unroll
        for (int ks = 0; ks < 2; ++ks) {
            bh8 af[2], bfr[4];
            #pragma unroll
            for (int i = 0; i < 2; ++i) af[i] = frag_ld(Ash, wr + i * 16 + (lane & 15), ks * 4, lane);
            #pragma unroll
            for (int j = 0; j < 4; ++j) bfr[j] = frag_ld(Bsh, wc + j * 16 + (lane & 15), ks * 4, lane);
            #pragma unroll
            for (int i = 0; i < 2; ++i)
                #pragma unroll
                for (int j = 0; j < 4; ++j)
                    acc[i][j] = __builtin_amdgcn_mfma_f32_16x16x32_bf16(af[i], bfr[j], acc[i][j], 0, 0, 0);
        }
        __syncthreads();
    }

    const int cc = lane & 15, g4 = (lane >> 4) * 4;
    #pragma unroll
    for (int j = 0; j < 4; ++j) {
        int col = n0 + wc + j * 16 + cc;
        float bv = bias[col];
        float sc = (col < 768) ? 0.18033688011112042f : 1.0f;
        #pragma unroll
        for (int i = 0; i < 2; ++i) {
            #pragma unroll
            for (int r = 0; r < 4; ++r) {
                int row = m0 + wr + i * 16 + g4 + r;
                Cout[(size_t)row * N + col] = f2bf((acc[i][j][r] + bv) * sc);
            }
        }
    }
}

// ---------------- GEMM 64x64 (output projection; 768 blocks = 3/CU) ----------------
__global__ __launch_bounds__(256) void gemm64(const unsigned short* __restrict__ A,
                                              const unsigned short* __restrict__ Bt,
                                              const float* __restrict__ bias,
                                              float* __restrict__ Cout,
                                              int M, int N, int K) {
    __shared__ __align__(16) unsigned short Ash[64 * 64];
    __shared__ __align__(16) unsigned short Bsh[64 * 64];
    const int m0 = blockIdx.y * 64, n0 = blockIdx.x * 64;
    const int tid = threadIdx.x, wid = tid >> 6, lane = tid & 63;
    const int wr = (wid >> 1) * 32, wc = (wid & 1) * 32;

    fx4 acc[2][2];
    #pragma unroll
    for (int i = 0; i < 2; ++i)
        #pragma unroll
        for (int j = 0; j < 2; ++j)
            acc[i][j] = (fx4){0.f, 0.f, 0.f, 0.f};

    for (int k0 = 0; k0 < K; k0 += 64) {
        #pragma unroll
        for (int g = 0; g < 2; ++g) {
            int rt = (wid * 2 + g) * 8;
            stage_rows8(A + (size_t)(m0 + rt) * K + k0, K, Ash + rt * 64, lane);
            stage_rows8(Bt + (size_t)(n0 + rt) * K + k0, K, Bsh + rt * 64, lane);
        }
        __syncthreads();
        #pragma unroll
        for (int ks = 0; ks < 2; ++ks) {
            bh8 af[2], bfr[2];
            #pragma unroll
            for (int i = 0; i < 2; ++i) af[i] = frag_ld(Ash, wr + i * 16 + (lane & 15), ks * 4, lane);
            #pragma unroll
            for (int j = 0; j < 2; ++j) bfr[j] = frag_ld(Bsh, wc + j * 16 + (lane & 15), ks * 4, lane);
            #pragma unroll
            for (int i = 0; i < 2; ++i)
                #pragma unroll
                for (int j = 0; j < 2; ++j)
                    acc[i][j] = __builtin_amdgcn_mfma_f32_16x16x32_bf16(af[i], bfr[j], acc[i][j], 0, 0, 0);
        }
        __syncthreads();
    }

    const int cc = lane & 15, g4 = (lane >> 4) * 4;
    #pragma unroll
    for (int j = 0; j < 2; ++j) {
        int col = n0 + wc + j * 16 + cc;
        float bv = bias[col];
        #pragma unroll
        for (int i = 0; i < 2; ++i) {
            #pragma unroll
            for (int r = 0; r < 4; ++r) {
                int row = m0 + wr + i * 16 + g4 + r;
                Cout[(size_t)row * N + col] = acc[i][j][r] + bv;
            }
        }
    }
}

// ---------------- flash attention: 2x2 wave split (q-half x kv-half), shift-0 softmax ----------------
// EXACT round-9 verified kernel (72.4 us, absmax 1.3e-4). Round 10's ones-MFMA l-trick
// REVERTED: it computed l from bf16-rounded P (absmax 5.2e-4, 92% of threshold) and
// serialized the PV chain (occupancy 24->17, +5.7 us).
__global__ __launch_bounds__(256) void attn_fwd(const unsigned short* __restrict__ qkv,
                                                const unsigned short* __restrict__ vt,
                                                unsigned short* __restrict__ ao) {
    __shared__ __align__(16) char smem[40960];
    unsigned short* Qs  = (unsigned short*)smem;              // [64*64] 8 KB
    unsigned short* Ks0 = (unsigned short*)(smem + 8192);
    unsigned short* Ks1 = (unsigned short*)(smem + 16384);
    unsigned short* Vs0 = (unsigned short*)(smem + 24576);
    unsigned short* Vs1 = (unsigned short*)(smem + 32768);
    float* Of    = (float*)smem;            // epilogue overlay: [64 q][68] f32 = 17408 B
    float* l_lds = (float*)(smem + 17408);  // [64] f32 (both overlay dead K/Q buffers)

    const int h = blockIdx.y, q0 = blockIdx.x * 64;
    const int tid = threadIdx.x, wid = tid >> 6, lane = tid & 63;
    const int g = lane >> 4, qc = lane & 15, x = qc & 7;
    const int wq = wid >> 1, wk = wid & 1;

    const unsigned short* qg_ = qkv + (size_t)q0 * 2304 + h * 64;
    const unsigned short* kgb = qkv + 768 + h * 64;
    const unsigned short* vgb = vt + (size_t)h * 64 * 4096;

    // stage Q tile + KV tile 0 (block-wide, same pattern as verified rounds)
    #pragma unroll
    for (int gg = 0; gg < 2; ++gg) {
        int rt = (wid * 2 + gg) * 8;
        stage_rows8(qg_ + (size_t)rt * 2304, 2304, Qs + rt * 64, lane);
        stage_rows8(kgb + (size_t)rt * 2304, 2304, Ks0 + rt * 64, lane);
        stage_rows8(vgb + (size_t)rt * 4096, 4096, Vs0 + rt * 64, lane);
    }
    __syncthreads();

    // Q fragments for this wave's q-half (2 q-groups x 2 k-chunks), in registers for good
    bh8 qf[2][2];
    #pragma unroll
    for (int qg = 0; qg < 2; ++qg)
        #pragma unroll
        for (int kc = 0; kc < 2; ++kc)
            qf[qg][kc] = frag_ld(Qs, 32 * wq + 16 * qg + qc, 4 * kc, lane);

    // hoisted per-lane LDS short-offsets (constant across the KV loop)
    int koff[2][2], voff[4];
    #pragma unroll
    for (int jm = 0; jm < 2; ++jm)
        #pragma unroll
        for (int kc = 0; kc < 2; ++kc)
            koff[jm][kc] = (32 * wk + 16 * jm + qc) * 64 + ((4 * kc + g) ^ x) * 8;
    #pragma unroll
    for (int dj = 0; dj < 4; ++dj)
        voff[dj] = (16 * dj + qc) * 64 + ((4 * wk + g) ^ x) * 8;

    float lrun[2] = {0.f, 0.f};
    fx4 oacP[4][2];   // [dj][qg], kv-partial O^T
    #pragma unroll
    for (int dj = 0; dj < 4; ++dj)
        #pragma unroll
        for (int qg = 0; qg < 2; ++qg)
            oacP[dj][qg] = (fx4){0.f, 0.f, 0.f, 0.f};

    const unsigned short* knext = kgb + (size_t)64 * 2304;
    const unsigned short* vnext = vgb + 64;

    auto tile_step = [&](const unsigned short* Kc, const unsigned short* Vc,
                         unsigned short* Kd, unsigned short* Vd, bool pref) {
        if (pref) {  // prefetch next KV tile (drained at the loop-end barrier)
            #pragma unroll
            for (int gg = 0; gg < 2; ++gg) {
                int rt = (wid * 2 + gg) * 8;
                stage_rows8(knext + (size_t)rt * 2304, 2304, Kd + rt * 64, lane);
                stage_rows8(vnext + (size_t)rt * 4096, 4096, Vd + rt * 64, lane);
            }
            knext += (size_t)64 * 2304;
            vnext += 64;
        }

        // S^T = K . Q^T over this wave's kv-half: sT[jm][qg] r = S^T[32wk+16jm+4g+r][32wq+16qg+qc]
        bh8 kf[2][2];
        #pragma unroll
        for (int jm = 0; jm < 2; ++jm) {
            kf[jm][0] = *(const bh8*)(Kc + koff[jm][0]);
            kf[jm][1] = *(const bh8*)(Kc + koff[jm][1]);
        }
        fx4 sT[2][2];
        __builtin_amdgcn_s_setprio(1);
        #pragma unroll
        for (int jm = 0; jm < 2; ++jm)
            #pragma unroll
            for (int qg = 0; qg < 2; ++qg) {
                fx4 z = (fx4){0.f, 0.f, 0.f, 0.f};
                z = __builtin_amdgcn_mfma_f32_16x16x32_bf16(kf[jm][0], qf[qg][0], z, 0, 0, 0);
                z = __builtin_amdgcn_mfma_f32_16x16x32_bf16(kf[jm][1], qf[qg][1], z, 0, 0, 0);
                sT[jm][qg] = z;
            }
        __builtin_amdgcn_s_setprio(0);

        // P = exp2(S^T) (Q pre-scaled by log2(e)/8; shift-0 safe, round-8 verified)
        #pragma unroll
        for (int jm = 0; jm < 2; ++jm)
            #pragma unroll
            for (int qg = 0; qg < 2; ++qg) {
                sT[jm][qg][0] = __builtin_amdgcn_exp2f(sT[jm][qg][0]);
                sT[jm][qg][1] = __builtin_amdgcn_exp2f(sT[jm][qg][1]);
                sT[jm][qg][2] = __builtin_amdgcn_exp2f(sT[jm][qg][2]);
                sT[jm][qg][3] = __builtin_amdgcn_exp2f(sT[jm][qg][3]);
                lrun[qg] += (sT[jm][qg][0] + sT[jm][qg][1]) + (sT[jm][qg][2] + sT[jm][qg][3]);
            }

        // O^T += V^T . P over kv-half (ks = wk): verified kappa machinery
        bh8 vf[4];
        #pragma unroll
        for (int dj = 0; dj < 4; ++dj) vf[dj] = *(const bh8*)(Vc + voff[dj]);
        __builtin_amdgcn_s_setprio(1);
        #pragma unroll
        for (int qg = 0; qg < 2; ++qg) {
            bh8 pb = pack4(cvtpk_bf16(sT[0][qg][0], sT[0][qg][1]),
                           cvtpk_bf16(sT[0][qg][2], sT[0][qg][3]),
                           cvtpk_bf16(sT[1][qg][0], sT[1][qg][1]),
                           cvtpk_bf16(sT[1][qg][2], sT[1][qg][3]));
            #pragma unroll
            for (int dj = 0; dj < 4; ++dj)
                oacP[dj][qg] = __builtin_amdgcn_mfma_f32_16x16x32_bf16(vf[dj], pb, oacP[dj][qg], 0, 0, 0);
        }
        __builtin_amdgcn_s_setprio(0);
        __syncthreads();  // one barrier/tile: drains prefetch + protects buffer swap
    };

    for (int t2 = 0; t2 < 32; ++t2) {
        tile_step(Ks0, Vs0, Ks1, Vs1, true);
        tile_step(Ks1, Vs1, Ks0, Vs0, t2 < 31);
    }

    // ---- epilogue: 2-way cross-wave (wk) reduction, then scale + store ----
    // fold the 4 g-copies of each q-row's partial l (lanes differ in bits 4..5)
    #pragma unroll
    for (int qg = 0; qg < 2; ++qg) {
        lrun[qg] += __shfl_xor(lrun[qg], 16);
        lrun[qg] += __shfl_xor(lrun[qg], 32);
    }
    // wk==1 waves publish partials into the LDS overlay (K/Q buffers are dead here)
    if (wk == 1) {
        #pragma unroll
        for (int qg = 0; qg < 2; ++qg) {
            int q = 32 * wq + 16 * qg + qc;
            #pragma unroll
            for (int dj = 0; dj < 4; ++dj)
                *(fx4*)(Of + q * 68 + 16 * dj + 4 * g) = oacP[dj][qg];
            l_lds[q] = lrun[qg];   // all 4 g-lanes write the same value
        }
    }
    __syncthreads();
    if (wk == 0) {
        #pragma unroll
        for (int qg = 0; qg < 2; ++qg) {
            int q = 32 * wq + 16 * qg + qc;
            float inv = 1.0f / (lrun[qg] + l_lds[q]);
            unsigned short* aop = ao + (size_t)(q0 + q) * 768 + h * 64;
            #pragma unroll
            for (int dj = 0; dj < 4; ++dj) {
                fx4 o = oacP[dj][qg];
                fx4 p = *(const fx4*)(Of + q * 68 + 16 * dj + 4 * g);
                int d0 = dj * 16 + 4 * g;
                *(unsigned int*)(aop + d0)     = cvtpk_bf16((o[0] + p[0]) * inv, (o[1] + p[1]) * inv);
                *(unsigned int*)(aop + d0 + 2) = cvtpk_bf16((o[2] + p[2]) * inv, (o[3] + p[3]) * inv);
            }
        }
    }
}

extern "C" void kernel_launch(void* const* d_in, const int* in_sizes, int n_in,
                              void* d_out, int out_size, void* d_ws, size_t ws_size,
                              hipStream_t stream) {
    const float* x     = (const float*)d_in[0];   // [4096,768]
    const float* w_qkv = (const float*)d_in[1];   // [768,2304]
    const float* b_qkv = (const float*)d_in[2];   // [2304]
    const float* w_out = (const float*)d_in[3];   // [768,768]
    const float* b_out = (const float*)d_in[4];   // [768]
    float* out = (float*)d_out;                   // [4096,768] fp32

    const int S = 4096, E = 768, E3 = 2304, H = 12;

    unsigned short* xb    = (unsigned short*)d_ws;          // S*E
    unsigned short* wqkvT = xb    + (size_t)S * E;          // E3*E
    unsigned short* woutT = wqkvT + (size_t)E3 * E;         // E*E
    unsigned short* qkvb  = woutT + (size_t)E * E;          // S*E3
    unsigned short* vtp   = qkvb  + (size_t)S * E3;         // H*64*S
    unsigned short* ao    = vtp   + (size_t)H * 64 * S;     // S*E

    castbf<<<dim3((S * E) / (256 * 4)), 256, 0, stream>>>(x, xb, S * E);
    transW<<<dim3(E3 / 32, E / 32), 256, 0, stream>>>(w_qkv, wqkvT, E, E3);
    transW<<<dim3(E / 32, E / 32), 256, 0, stream>>>(w_out, woutT, E, E);
    gemm_qkv<<<dim3(E3 / 128, S / 64), 256, 0, stream>>>(xb, wqkvT, b_qkv, qkvb, S, E3, E);
    transV<<<dim3(S / 64, H), 256, 0, stream>>>(qkvb, vtp);
    attn_fwd<<<dim3(S / 64, H), 256, 0, stream>>>(qkvb, vtp, ao);
    gemm64<<<dim3(E / 64, S / 64), 256, 0, stream>>>(ao, woutT, b_out, out, S, E, E);
}

// Round 12
// 119.179 us; speedup vs baseline: 1.1297x; 1.0462x over previous
//
#include <hip/hip_runtime.h>

typedef __attribute__((ext_vector_type(8))) short bh8;   // 8 x bf16 (4 VGPRs)
typedef __attribute__((ext_vector_type(4))) float fx4;   // 16x16 MFMA accumulator

__device__ __forceinline__ unsigned short f2bf(float f) {
    unsigned int u = __float_as_uint(f);
    u += 0x7FFF + ((u >> 16) & 1);          // RNE
    return (unsigned short)(u >> 16);
}

// pack 2 f32 -> 2 bf16 in one u32 (RNE), low = a, high = b
__device__ __forceinline__ unsigned int cvtpk_bf16(float a, float b) {
    unsigned int r;
    asm("v_cvt_pk_bf16_f32 %0, %1, %2" : "=v"(r) : "v"(a), "v"(b));
    return r;
}

__device__ __forceinline__ bh8 pack4(unsigned int a, unsigned int b,
                                     unsigned int c, unsigned int d) {
    union { unsigned int u[4]; bh8 h; } z;
    z.u[0] = a; z.u[1] = b; z.u[2] = c; z.u[3] = d;
    return z.h;
}

// Stage 8 rows x 64 bf16 cols into LDS (linear dest) via global_load_lds width=16.
// Global source chunk is XOR-swizzled by row&7 (rule #21: swizzle source + read).
__device__ __forceinline__ void stage_rows8(const unsigned short* g, long ldg,
                                            unsigned short* lds, int lane) {
    int r8 = lane >> 3;
    int gc = (lane & 7) ^ r8;
    __builtin_amdgcn_global_load_lds(
        (const __attribute__((address_space(1))) void*)(g + (long)r8 * ldg + gc * 8),
        (__attribute__((address_space(3))) void*)lds, 16, 0, 0);
}

// 16x16x32 fragment read from a swizzled [rows][64] tile (VERIFIED in passing gemms):
// logical k-chunk = kchunk + (lane>>4), stored at chunk^(row&7).
__device__ __forceinline__ bh8 frag_ld(const unsigned short* t, int row, int kchunk, int lane) {
    int ch = (kchunk + (lane >> 4)) ^ (row & 7);
    return *(const bh8*)(t + row * 64 + ch * 8);
}

// ---------------- cast fp32 -> bf16 ----------------
__global__ __launch_bounds__(256) void castbf(const float* __restrict__ x,
                                              unsigned short* __restrict__ y, int n) {
    int i = (blockIdx.x * 256 + threadIdx.x) * 4;
    if (i < n) {
        float4 v = *(const float4*)(x + i);
        ushort4 o = make_ushort4(f2bf(v.x), f2bf(v.y), f2bf(v.z), f2bf(v.w));
        *(ushort4*)(y + i) = o;
    }
}

// ---------------- transpose + cast W[K][N] fp32 -> Wt[N][K] bf16 ----------------
__global__ __launch_bounds__(256) void transW(const float* __restrict__ W,
                                              unsigned short* __restrict__ Wt,
                                              int K, int N) {
    __shared__ float t[32][33];
    const int n0 = blockIdx.x * 32, k0 = blockIdx.y * 32;
    const int tx = threadIdx.x & 31, ty = threadIdx.x >> 5;
    #pragma unroll
    for (int r = ty; r < 32; r += 8)
        t[r][tx] = W[(size_t)(k0 + r) * N + n0 + tx];
    __syncthreads();
    #pragma unroll
    for (int r = ty; r < 32; r += 8)
        Wt[(size_t)(n0 + r) * K + k0 + tx] = f2bf(t[tx][r]);
}

// ---------------- QKV GEMM, 64x128 tile, single-barrier double-buffered prefetch ----------------
// Schedule = attn's verified tile_step: issue stage(t+1) -> compute(t) -> one barrier.
// Q cols [0,768) pre-scaled by log2(e)/8. V cols [1536,2304) are NOT written to Cout:
// they go through a padded LDS transpose and land directly in vt[h*64+d][4096] with the
// verified px permutation pos(32a+16b+4g+r)=32a+8g+4b+r (fuses the old transV kernel).
// Inverse used on read-out: y=32a+8g+4b+r -> s=(y&32)+((y&4)<<2)+((y&24)>>1)+(y&3).
__global__ __launch_bounds__(256) void gemm_qkv(const unsigned short* __restrict__ A,
                                                const unsigned short* __restrict__ Bt,
                                                const float* __restrict__ bias,
                                                unsigned short* __restrict__ Cout,
                                                unsigned short* __restrict__ vt) {
    const int M = 4096, N = 2304, K = 768;
    __shared__ __align__(16) char smem[49152];
    unsigned short* Ash0 = (unsigned short*)smem;             // 8 KB
    unsigned short* Ash1 = (unsigned short*)(smem + 8192);
    unsigned short* Bsh0 = (unsigned short*)(smem + 16384);   // 16 KB
    unsigned short* Bsh1 = (unsigned short*)(smem + 32768);
    unsigned short* Tsc  = (unsigned short*)smem;             // V-transpose scratch [128][68] (17.4 KB, overlays dead bufs)

    const int m0 = blockIdx.y * 64, n0 = blockIdx.x * 128;
    const int tid = threadIdx.x, wid = tid >> 6, lane = tid & 63;
    const int wr = (wid >> 1) * 32, wc = (wid & 1) * 64;

    // stage K-step 0
    #pragma unroll
    for (int g = 0; g < 2; ++g) {
        int rt = (wid * 2 + g) * 8;
        stage_rows8(A + (size_t)(m0 + rt) * K, K, Ash0 + rt * 64, lane);
    }
    #pragma unroll
    for (int g = 0; g < 4; ++g) {
        int rt = (wid * 4 + g) * 8;
        stage_rows8(Bt + (size_t)(n0 + rt) * K, K, Bsh0 + rt * 64, lane);
    }
    __syncthreads();

    fx4 acc[2][4];
    #pragma unroll
    for (int i = 0; i < 2; ++i)
        #pragma unroll
        for (int j = 0; j < 4; ++j)
            acc[i][j] = (fx4){0.f, 0.f, 0.f, 0.f};

    int kn = 64;
    auto kstep = [&](const unsigned short* Ac, const unsigned short* Bc,
                     unsigned short* Ad, unsigned short* Bd, bool pref) {
        if (pref) {  // prefetch next K-slab (drained at the loop-end barrier)
            #pragma unroll
            for (int g = 0; g < 2; ++g) {
                int rt = (wid * 2 + g) * 8;
                stage_rows8(A + (size_t)(m0 + rt) * K + kn, K, Ad + rt * 64, lane);
            }
            #pragma unroll
            for (int g = 0; g < 4; ++g) {
                int rt = (wid * 4 + g) * 8;
                stage_rows8(Bt + (size_t)(n0 + rt) * K + kn, K, Bd + rt * 64, lane);
            }
            kn += 64;
        }
        #pragma unroll
        for (int ks = 0; ks < 2; ++ks) {
            bh8 af[2], bfr[4];
            #pragma unroll
            for (int i = 0; i < 2; ++i) af[i] = frag_ld(Ac, wr + i * 16 + (lane & 15), ks * 4, lane);
            #pragma unroll
            for (int j = 0; j < 4; ++j) bfr[j] = frag_ld(Bc, wc + j * 16 + (lane & 15), ks * 4, lane);
            #pragma unroll
            for (int i = 0; i < 2; ++i)
                #pragma unroll
                for (int j = 0; j < 4; ++j)
                    acc[i][j] = __builtin_amdgcn_mfma_f32_16x16x32_bf16(af[i], bfr[j], acc[i][j], 0, 0, 0);
        }
        __syncthreads();
    };

    for (int t2 = 0; t2 < 6; ++t2) {             // 12 K-steps of 64
        kstep(Ash0, Bsh0, Ash1, Bsh1, true);
        kstep(Ash1, Bsh1, Ash0, Bsh0, t2 < 5);
    }

    const int cc = lane & 15, g4 = (lane >> 4) * 4;
    if (n0 < 1536) {
        // Q/K blocks: plain store to qkvb (Q cols scaled)
        #pragma unroll
        for (int j = 0; j < 4; ++j) {
            int col = n0 + wc + j * 16 + cc;
            float bv = bias[col];
            float sc = (col < 768) ? 0.18033688011112042f : 1.0f;
            #pragma unroll
            for (int i = 0; i < 2; ++i) {
                #pragma unroll
                for (int r = 0; r < 4; ++r) {
                    int row = m0 + wr + i * 16 + g4 + r;
                    Cout[(size_t)row * N + col] = f2bf((acc[i][j][r] + bv) * sc);
                }
            }
        }
    } else {
        // V block: acc -> Tsc[d][s] (stride 68 breaks write conflicts), then permuted
        // coalesced row writes to vt (replaces the transV kernel; same RNE numerics).
        #pragma unroll
        for (int j = 0; j < 4; ++j) {
            int dloc = wc + j * 16 + cc;
            float bv = bias[n0 + dloc];
            #pragma unroll
            for (int i = 0; i < 2; ++i) {
                int sloc = wr + i * 16 + g4;
                unsigned int u0 = cvtpk_bf16(acc[i][j][0] + bv, acc[i][j][1] + bv);
                unsigned int u1 = cvtpk_bf16(acc[i][j][2] + bv, acc[i][j][3] + bv);
                *(uint2*)(Tsc + dloc * 68 + sloc) = make_uint2(u0, u1);
            }
        }
        __syncthreads();
        const int d = tid >> 1, hf = (tid & 1) << 5;
        const unsigned short* srow = Tsc + d * 68;
        unsigned short* dst = vt + (size_t)(n0 - 1536 + d) * 4096 + m0 + hf;
        #pragma unroll
        for (int k = 0; k < 4; ++k) {
            int y = hf + 8 * k;
            int sb = (y & 32) + ((y & 24) >> 1);      // inverse-perm base; +16 for b=1
            uint2 lo = *(const uint2*)(srow + sb);
            uint2 hi = *(const uint2*)(srow + sb + 16);
            *(uint4*)(dst + 8 * k) = make_uint4(lo.x, lo.y, hi.x, hi.y);
        }
    }
}

// ---------------- GEMM 64x64 (output projection), single-barrier double-buffered ----------------
__global__ __launch_bounds__(256) void gemm64(const unsigned short* __restrict__ A,
                                              const unsigned short* __restrict__ Bt,
                                              const float* __restrict__ bias,
                                              float* __restrict__ Cout,
                                              int M, int N, int K) {
    __shared__ __align__(16) unsigned short Ash[2][64 * 64];
    __shared__ __align__(16) unsigned short Bsh[2][64 * 64];
    const int m0 = blockIdx.y * 64, n0 = blockIdx.x * 64;
    const int tid = threadIdx.x, wid = tid >> 6, lane = tid & 63;
    const int wr = (wid >> 1) * 32, wc = (wid & 1) * 32;

    #pragma unroll
    for (int g = 0; g < 2; ++g) {
        int rt = (wid * 2 + g) * 8;
        stage_rows8(A + (size_t)(m0 + rt) * K, K, Ash[0] + rt * 64, lane);
        stage_rows8(Bt + (size_t)(n0 + rt) * K, K, Bsh[0] + rt * 64, lane);
    }
    __syncthreads();

    fx4 acc[2][2];
    #pragma unroll
    for (int i = 0; i < 2; ++i)
        #pragma unroll
        for (int j = 0; j < 2; ++j)
            acc[i][j] = (fx4){0.f, 0.f, 0.f, 0.f};

    int kn = 64;
    auto kstep = [&](const unsigned short* Ac, const unsigned short* Bc,
                     unsigned short* Ad, unsigned short* Bd, bool pref) {
        if (pref) {
            #pragma unroll
            for (int g = 0; g < 2; ++g) {
                int rt = (wid * 2 + g) * 8;
                stage_rows8(A + (size_t)(m0 + rt) * K + kn, K, Ad + rt * 64, lane);
                stage_rows8(Bt + (size_t)(n0 + rt) * K + kn, K, Bd + rt * 64, lane);
            }
            kn += 64;
        }
        #pragma unroll
        for (int ks = 0; ks < 2; ++ks) {
            bh8 af[2], bfr[2];
            #pragma unroll
            for (int i = 0; i < 2; ++i) af[i] = frag_ld(Ac, wr + i * 16 + (lane & 15), ks * 4, lane);
            #pragma unroll
            for (int j = 0; j < 2; ++j) bfr[j] = frag_ld(Bc, wc + j * 16 + (lane & 15), ks * 4, lane);
            #pragma unroll
            for (int i = 0; i < 2; ++i)
                #pragma unroll
                for (int j = 0; j < 2; ++j)
                    acc[i][j] = __builtin_amdgcn_mfma_f32_16x16x32_bf16(af[i], bfr[j], acc[i][j], 0, 0, 0);
        }
        __syncthreads();
    };

    for (int t2 = 0; t2 < 6; ++t2) {             // K=768: 12 steps
        kstep(Ash[0], Bsh[0], Ash[1], Bsh[1], true);
        kstep(Ash[1], Bsh[1], Ash[0], Bsh[0], t2 < 5);
    }

    const int cc = lane & 15, g4 = (lane >> 4) * 4;
    #pragma unroll
    for (int j = 0; j < 2; ++j) {
        int col = n0 + wc + j * 16 + cc;
        float bv = bias[col];
        #pragma unroll
        for (int i = 0; i < 2; ++i) {
            #pragma unroll
            for (int r = 0; r < 4; ++r) {
                int row = m0 + wr + i * 16 + g4 + r;
                Cout[(size_t)row * N + col] = acc[i][j][r] + bv;
            }
        }
    }
}

// ---------------- flash attention: 2x2 wave split (q-half x kv-half), shift-0 softmax ----------------
// EXACT round-9/11 verified kernel (72.4 us, absmax 1.3e-4). Unchanged this round.
__global__ __launch_bounds__(256) void attn_fwd(const unsigned short* __restrict__ qkv,
                                                const unsigned short* __restrict__ vt,
                                                unsigned short* __restrict__ ao) {
    __shared__ __align__(16) char smem[40960];
    unsigned short* Qs  = (unsigned short*)smem;              // [64*64] 8 KB
    unsigned short* Ks0 = (unsigned short*)(smem + 8192);
    unsigned short* Ks1 = (unsigned short*)(smem + 16384);
    unsigned short* Vs0 = (unsigned short*)(smem + 24576);
    unsigned short* Vs1 = (unsigned short*)(smem + 32768);
    float* Of    = (float*)smem;            // epilogue overlay: [64 q][68] f32 = 17408 B
    float* l_lds = (float*)(smem + 17408);  // [64] f32 (both overlay dead K/Q buffers)

    const int h = blockIdx.y, q0 = blockIdx.x * 64;
    const int tid = threadIdx.x, wid = tid >> 6, lane = tid & 63;
    const int g = lane >> 4, qc = lane & 15, x = qc & 7;
    const int wq = wid >> 1, wk = wid & 1;

    const unsigned short* qg_ = qkv + (size_t)q0 * 2304 + h * 64;
    const unsigned short* kgb = qkv + 768 + h * 64;
    const unsigned short* vgb = vt + (size_t)h * 64 * 4096;

    #pragma unroll
    for (int gg = 0; gg < 2; ++gg) {
        int rt = (wid * 2 + gg) * 8;
        stage_rows8(qg_ + (size_t)rt * 2304, 2304, Qs + rt * 64, lane);
        stage_rows8(kgb + (size_t)rt * 2304, 2304, Ks0 + rt * 64, lane);
        stage_rows8(vgb + (size_t)rt * 4096, 4096, Vs0 + rt * 64, lane);
    }
    __syncthreads();

    bh8 qf[2][2];
    #pragma unroll
    for (int qg = 0; qg < 2; ++qg)
        #pragma unroll
        for (int kc = 0; kc < 2; ++kc)
            qf[qg][kc] = frag_ld(Qs, 32 * wq + 16 * qg + qc, 4 * kc, lane);

    int koff[2][2], voff[4];
    #pragma unroll
    for (int jm = 0; jm < 2; ++jm)
        #pragma unroll
        for (int kc = 0; kc < 2; ++kc)
            koff[jm][kc] = (32 * wk + 16 * jm + qc) * 64 + ((4 * kc + g) ^ x) * 8;
    #pragma unroll
    for (int dj = 0; dj < 4; ++dj)
        voff[dj] = (16 * dj + qc) * 64 + ((4 * wk + g) ^ x) * 8;

    float lrun[2] = {0.f, 0.f};
    fx4 oacP[4][2];
    #pragma unroll
    for (int dj = 0; dj < 4; ++dj)
        #pragma unroll
        for (int qg = 0; qg < 2; ++qg)
            oacP[dj][qg] = (fx4){0.f, 0.f, 0.f, 0.f};

    const unsigned short* knext = kgb + (size_t)64 * 2304;
    const unsigned short* vnext = vgb + 64;

    auto tile_step = [&](const unsigned short* Kc, const unsigned short* Vc,
                         unsigned short* Kd, unsigned short* Vd, bool pref) {
        if (pref) {
            #pragma unroll
            for (int gg = 0; gg < 2; ++gg) {
                int rt = (wid * 2 + gg) * 8;
                stage_rows8(knext + (size_t)rt * 2304, 2304, Kd + rt * 64, lane);
                stage_rows8(vnext + (size_t)rt * 4096, 4096, Vd + rt * 64, lane);
            }
            knext += (size_t)64 * 2304;
            vnext += 64;
        }

        bh8 kf[2][2];
        #pragma unroll
        for (int jm = 0; jm < 2; ++jm) {
            kf[jm][0] = *(const bh8*)(Kc + koff[jm][0]);
            kf[jm][1] = *(const bh8*)(Kc + koff[jm][1]);
        }
        fx4 sT[2][2];
        __builtin_amdgcn_s_setprio(1);
        #pragma unroll
        for (int jm = 0; jm < 2; ++jm)
            #pragma unroll
            for (int qg = 0; qg < 2; ++qg) {
                fx4 z = (fx4){0.f, 0.f, 0.f, 0.f};
                z = __builtin_amdgcn_mfma_f32_16x16x32_bf16(kf[jm][0], qf[qg][0], z, 0, 0, 0);
                z = __builtin_amdgcn_mfma_f32_16x16x32_bf16(kf[jm][1], qf[qg][1], z, 0, 0, 0);
                sT[jm][qg] = z;
            }
        __builtin_amdgcn_s_setprio(0);

        #pragma unroll
        for (int jm = 0; jm < 2; ++jm)
            #pragma unroll
            for (int qg = 0; qg < 2; ++qg) {
                sT[jm][qg][0] = __builtin_amdgcn_exp2f(sT[jm][qg][0]);
                sT[jm][qg][1] = __builtin_amdgcn_exp2f(sT[jm][qg][1]);
                sT[jm][qg][2] = __builtin_amdgcn_exp2f(sT[jm][qg][2]);
                sT[jm][qg][3] = __builtin_amdgcn_exp2f(sT[jm][qg][3]);
                lrun[qg] += (sT[jm][qg][0] + sT[jm][qg][1]) + (sT[jm][qg][2] + sT[jm][qg][3]);
            }

        bh8 vf[4];
        #pragma unroll
        for (int dj = 0; dj < 4; ++dj) vf[dj] = *(const bh8*)(Vc + voff[dj]);
        __builtin_amdgcn_s_setprio(1);
        #pragma unroll
        for (int qg = 0; qg < 2; ++qg) {
            bh8 pb = pack4(cvtpk_bf16(sT[0][qg][0], sT[0][qg][1]),
                           cvtpk_bf16(sT[0][qg][2], sT[0][qg][3]),
                           cvtpk_bf16(sT[1][qg][0], sT[1][qg][1]),
                           cvtpk_bf16(sT[1][qg][2], sT[1][qg][3]));
            #pragma unroll
            for (int dj = 0; dj < 4; ++dj)
                oacP[dj][qg] = __builtin_amdgcn_mfma_f32_16x16x32_bf16(vf[dj], pb, oacP[dj][qg], 0, 0, 0);
        }
        __builtin_amdgcn_s_setprio(0);
        __syncthreads();
    };

    for (int t2 = 0; t2 < 32; ++t2) {
        tile_step(Ks0, Vs0, Ks1, Vs1, true);
        tile_step(Ks1, Vs1, Ks0, Vs0, t2 < 31);
    }

    #pragma unroll
    for (int qg = 0; qg < 2; ++qg) {
        lrun[qg] += __shfl_xor(lrun[qg], 16);
        lrun[qg] += __shfl_xor(lrun[qg], 32);
    }
    if (wk == 1) {
        #pragma unroll
        for (int qg = 0; qg < 2; ++qg) {
            int q = 32 * wq + 16 * qg + qc;
            #pragma unroll
            for (int dj = 0; dj < 4; ++dj)
                *(fx4*)(Of + q * 68 + 16 * dj + 4 * g) = oacP[dj][qg];
            l_lds[q] = lrun[qg];
        }
    }
    __syncthreads();
    if (wk == 0) {
        #pragma unroll
        for (int qg = 0; qg < 2; ++qg) {
            int q = 32 * wq + 16 * qg + qc;
            float inv = 1.0f / (lrun[qg] + l_lds[q]);
            unsigned short* aop = ao + (size_t)(q0 + q) * 768 + h * 64;
            #pragma unroll
            for (int dj = 0; dj < 4; ++dj) {
                fx4 o = oacP[dj][qg];
                fx4 p = *(const fx4*)(Of + q * 68 + 16 * dj + 4 * g);
                int d0 = dj * 16 + 4 * g;
                *(unsigned int*)(aop + d0)     = cvtpk_bf16((o[0] + p[0]) * inv, (o[1] + p[1]) * inv);
                *(unsigned int*)(aop + d0 + 2) = cvtpk_bf16((o[2] + p[2]) * inv, (o[3] + p[3]) * inv);
            }
        }
    }
}

extern "C" void kernel_launch(void* const* d_in, const int* in_sizes, int n_in,
                              void* d_out, int out_size, void* d_ws, size_t ws_size,
                              hipStream_t stream) {
    const float* x     = (const float*)d_in[0];   // [4096,768]
    const float* w_qkv = (const float*)d_in[1];   // [768,2304]
    const float* b_qkv = (const float*)d_in[2];   // [2304]
    const float* w_out = (const float*)d_in[3];   // [768,768]
    const float* b_out = (const float*)d_in[4];   // [768]
    float* out = (float*)d_out;                   // [4096,768] fp32

    const int S = 4096, E = 768, E3 = 2304, H = 12;

    unsigned short* xb    = (unsigned short*)d_ws;          // S*E
    unsigned short* wqkvT = xb    + (size_t)S * E;          // E3*E
    unsigned short* woutT = wqkvT + (size_t)E3 * E;         // E*E
    unsigned short* qkvb  = woutT + (size_t)E * E;          // S*E3 (V third unused)
    unsigned short* vtp   = qkvb  + (size_t)S * E3;         // H*64*S
    unsigned short* ao    = vtp   + (size_t)H * 64 * S;     // S*E

    castbf<<<dim3((S * E) / (256 * 4)), 256, 0, stream>>>(x, xb, S * E);
    transW<<<dim3(E3 / 32, E / 32), 256, 0, stream>>>(w_qkv, wqkvT, E, E3);
    transW<<<dim3(E / 32, E / 32), 256, 0, stream>>>(w_out, woutT, E, E);
    gemm_qkv<<<dim3(E3 / 128, S / 64), 256, 0, stream>>>(xb, wqkvT, b_qkv, qkvb, vtp);
    attn_fwd<<<dim3(S / 64, H), 256, 0, stream>>>(qkvb, vtp, ao);
    gemm64<<<dim3(E / 64, S / 64), 256, 0, stream>>>(ao, woutT, b_out, out, S, E, E);
}

// Round 13
// 116.931 us; speedup vs baseline: 1.1515x; 1.0192x over previous
//
#include <hip/hip_runtime.h>

typedef __attribute__((ext_vector_type(8))) short bh8;   // 8 x bf16 (4 VGPRs)
typedef __attribute__((ext_vector_type(4))) float fx4;   // 16x16 MFMA accumulator

__device__ __forceinline__ unsigned short f2bf(float f) {
    unsigned int u = __float_as_uint(f);
    u += 0x7FFF + ((u >> 16) & 1);          // RNE
    return (unsigned short)(u >> 16);
}

// pack 2 f32 -> 2 bf16 in one u32 (RNE), low = a, high = b
__device__ __forceinline__ unsigned int cvtpk_bf16(float a, float b) {
    unsigned int r;
    asm("v_cvt_pk_bf16_f32 %0, %1, %2" : "=v"(r) : "v"(a), "v"(b));
    return r;
}

__device__ __forceinline__ bh8 pack4(unsigned int a, unsigned int b,
                                     unsigned int c, unsigned int d) {
    union { unsigned int u[4]; bh8 h; } z;
    z.u[0] = a; z.u[1] = b; z.u[2] = c; z.u[3] = d;
    return z.h;
}

// Stage 8 rows x 64 bf16 cols into LDS (linear dest) via global_load_lds width=16.
// Global source chunk is XOR-swizzled by row&7 (rule #21: swizzle source + read).
__device__ __forceinline__ void stage_rows8(const unsigned short* g, long ldg,
                                            unsigned short* lds, int lane) {
    int r8 = lane >> 3;
    int gc = (lane & 7) ^ r8;
    __builtin_amdgcn_global_load_lds(
        (const __attribute__((address_space(1))) void*)(g + (long)r8 * ldg + gc * 8),
        (__attribute__((address_space(3))) void*)lds, 16, 0, 0);
}

// 16x16x32 fragment read from a swizzled [rows][64] tile (VERIFIED in passing gemms):
// logical k-chunk = kchunk + (lane>>4), stored at chunk^(row&7).
__device__ __forceinline__ bh8 frag_ld(const unsigned short* t, int row, int kchunk, int lane) {
    int ch = (kchunk + (lane >> 4)) ^ (row & 7);
    return *(const bh8*)(t + row * 64 + ch * 8);
}

// ---------------- merged prep: castbf (x->bf16) + transW(w_qkv) + transW(w_out) ----------------
// One kernel, 1D grid, block-range decode: saves 2 launch gaps vs 3 kernels.
__global__ __launch_bounds__(256) void prep(const float* __restrict__ x,
                                            unsigned short* __restrict__ xb,
                                            const float* __restrict__ w_qkv,
                                            unsigned short* __restrict__ wqkvT,
                                            const float* __restrict__ w_out,
                                            unsigned short* __restrict__ woutT) {
    __shared__ float t[32][33];
    const int bid = blockIdx.x;
    if (bid < 3072) {                       // castbf: 4096*768 elems / 1024 per block
        int i = (bid * 256 + threadIdx.x) * 4;
        float4 v = *(const float4*)(x + i);
        *(ushort4*)(xb + i) = make_ushort4(f2bf(v.x), f2bf(v.y), f2bf(v.z), f2bf(v.w));
        return;
    }
    const float* W; unsigned short* Wt; int N, xid;
    if (bid < 3072 + 1728) { W = w_qkv; Wt = wqkvT; N = 2304; xid = bid - 3072; }
    else                   { W = w_out; Wt = woutT; N = 768;  xid = bid - 4800; }
    const int K = 768, nb = N / 32;
    const int n0 = (xid % nb) * 32, k0 = (xid / nb) * 32;
    const int tx = threadIdx.x & 31, ty = threadIdx.x >> 5;
    #pragma unroll
    for (int r = ty; r < 32; r += 8)
        t[r][tx] = W[(size_t)(k0 + r) * N + n0 + tx];
    __syncthreads();
    #pragma unroll
    for (int r = ty; r < 32; r += 8)
        Wt[(size_t)(n0 + r) * K + k0 + tx] = f2bf(t[tx][r]);
}

// ---------------- QKV GEMM, 128x128 tile, dbuf single-barrier, XCD-swizzled ----------------
// BM=128 halves B L2-traffic vs BM=64 (113 vs 226 MB). Grid 1D 576 (=18n x 32m), bijective
// XCD swizzle (576%8==0): 72 contiguous blocks per XCD = 4 A-slabs + B panel ~ 4.3MB ~ L2.
// Schedule = verified r12 dbuf kstep. Q cols [0,768) pre-scaled by log2(e)/8.
// V cols [1536,2304): padded-LDS transpose -> vt with the verified pos() permutation
// pos(32a+16b+4g+r)=32a+8g+4b+r, applied independently per 64-s block (BM=128 -> 2 blocks,
// selected by tid&1). Inverse chunk base sb=(y&32)+((y&24)>>1), +16 for the b=1 half.
__global__ __launch_bounds__(256) void gemm_qkv(const unsigned short* __restrict__ A,
                                                const unsigned short* __restrict__ Bt,
                                                const float* __restrict__ bias,
                                                unsigned short* __restrict__ Cout,
                                                unsigned short* __restrict__ vt) {
    const int N = 2304, K = 768;
    __shared__ __align__(16) char smem[65536];
    unsigned short* Ash0 = (unsigned short*)smem;             // 16 KB each
    unsigned short* Ash1 = (unsigned short*)(smem + 16384);
    unsigned short* Bsh0 = (unsigned short*)(smem + 32768);
    unsigned short* Bsh1 = (unsigned short*)(smem + 49152);
    unsigned short* Tsc  = (unsigned short*)smem;             // V scratch [128][132] = 33.8 KB overlay

    const int bid = blockIdx.x;
    const int swz = (bid & 7) * 72 + (bid >> 3);
    const int m0 = (swz / 18) * 128, n0 = (swz % 18) * 128;
    const int tid = threadIdx.x, wid = tid >> 6, lane = tid & 63;
    const int wr = (wid >> 1) * 64, wc = (wid & 1) * 64;

    // stage K-step 0
    #pragma unroll
    for (int g = 0; g < 4; ++g) {
        int rt = (wid * 4 + g) * 8;
        stage_rows8(A + (size_t)(m0 + rt) * K, K, Ash0 + rt * 64, lane);
        stage_rows8(Bt + (size_t)(n0 + rt) * K, K, Bsh0 + rt * 64, lane);
    }
    __syncthreads();

    fx4 acc[4][4];
    #pragma unroll
    for (int i = 0; i < 4; ++i)
        #pragma unroll
        for (int j = 0; j < 4; ++j)
            acc[i][j] = (fx4){0.f, 0.f, 0.f, 0.f};

    int kn = 64;
    auto kstep = [&](const unsigned short* Ac, const unsigned short* Bc,
                     unsigned short* Ad, unsigned short* Bd, bool pref) {
        if (pref) {  // prefetch next K-slab (drained at the loop-end barrier)
            #pragma unroll
            for (int g = 0; g < 4; ++g) {
                int rt = (wid * 4 + g) * 8;
                stage_rows8(A + (size_t)(m0 + rt) * K + kn, K, Ad + rt * 64, lane);
                stage_rows8(Bt + (size_t)(n0 + rt) * K + kn, K, Bd + rt * 64, lane);
            }
            kn += 64;
        }
        #pragma unroll
        for (int ks = 0; ks < 2; ++ks) {
            bh8 af[4], bfr[4];
            #pragma unroll
            for (int i = 0; i < 4; ++i) af[i] = frag_ld(Ac, wr + i * 16 + (lane & 15), ks * 4, lane);
            #pragma unroll
            for (int j = 0; j < 4; ++j) bfr[j] = frag_ld(Bc, wc + j * 16 + (lane & 15), ks * 4, lane);
            #pragma unroll
            for (int i = 0; i < 4; ++i)
                #pragma unroll
                for (int j = 0; j < 4; ++j)
                    acc[i][j] = __builtin_amdgcn_mfma_f32_16x16x32_bf16(af[i], bfr[j], acc[i][j], 0, 0, 0);
        }
        __syncthreads();
    };

    for (int t2 = 0; t2 < 6; ++t2) {             // 12 K-steps of 64
        kstep(Ash0, Bsh0, Ash1, Bsh1, true);
        kstep(Ash1, Bsh1, Ash0, Bsh0, t2 < 5);
    }

    const int cc = lane & 15, g4 = (lane >> 4) * 4;
    if (n0 < 1536) {
        // Q/K blocks: plain store to qkvb (Q cols scaled)
        #pragma unroll
        for (int j = 0; j < 4; ++j) {
            int col = n0 + wc + j * 16 + cc;
            float bv = bias[col];
            float sc = (col < 768) ? 0.18033688011112042f : 1.0f;
            #pragma unroll
            for (int i = 0; i < 4; ++i) {
                #pragma unroll
                for (int r = 0; r < 4; ++r) {
                    int row = m0 + wr + i * 16 + g4 + r;
                    Cout[(size_t)row * N + col] = f2bf((acc[i][j][r] + bv) * sc);
                }
            }
        }
    } else {
        // V block: acc -> Tsc[d][s] (stride 132 breaks write conflicts), then permuted
        // coalesced row writes to vt (fused transV; same RNE numerics as r12-verified path).
        #pragma unroll
        for (int j = 0; j < 4; ++j) {
            int dloc = wc + j * 16 + cc;
            float bv = bias[n0 + dloc];
            #pragma unroll
            for (int i = 0; i < 4; ++i) {
                int sloc = wr + i * 16 + g4;
                unsigned int u0 = cvtpk_bf16(acc[i][j][0] + bv, acc[i][j][1] + bv);
                unsigned int u1 = cvtpk_bf16(acc[i][j][2] + bv, acc[i][j][3] + bv);
                *(uint2*)(Tsc + dloc * 132 + sloc) = make_uint2(u0, u1);
            }
        }
        __syncthreads();
        const int d = tid >> 1, bblk = tid & 1;
        const unsigned short* srow = Tsc + d * 132 + bblk * 64;
        unsigned short* dst = vt + (size_t)(n0 - 1536 + d) * 4096 + m0 + bblk * 64;
        #pragma unroll
        for (int k = 0; k < 8; ++k) {
            int y = 8 * k;
            int sb = (y & 32) + ((y & 24) >> 1);      // inverse-perm base; +16 for b=1
            uint2 lo = *(const uint2*)(srow + sb);
            uint2 hi = *(const uint2*)(srow + sb + 16);
            *(uint4*)(dst + 8 * k) = make_uint4(lo.x, lo.y, hi.x, hi.y);
        }
    }
}

// ---------------- GEMM 64x64 (output projection), single-barrier double-buffered ----------------
__global__ __launch_bounds__(256) void gemm64(const unsigned short* __restrict__ A,
                                              const unsigned short* __restrict__ Bt,
                                              const float* __restrict__ bias,
                                              float* __restrict__ Cout,
                                              int M, int N, int K) {
    __shared__ __align__(16) unsigned short Ash[2][64 * 64];
    __shared__ __align__(16) unsigned short Bsh[2][64 * 64];
    const int m0 = blockIdx.y * 64, n0 = blockIdx.x * 64;
    const int tid = threadIdx.x, wid = tid >> 6, lane = tid & 63;
    const int wr = (wid >> 1) * 32, wc = (wid & 1) * 32;

    #pragma unroll
    for (int g = 0; g < 2; ++g) {
        int rt = (wid * 2 + g) * 8;
        stage_rows8(A + (size_t)(m0 + rt) * K, K, Ash[0] + rt * 64, lane);
        stage_rows8(Bt + (size_t)(n0 + rt) * K, K, Bsh[0] + rt * 64, lane);
    }
    __syncthreads();

    fx4 acc[2][2];
    #pragma unroll
    for (int i = 0; i < 2; ++i)
        #pragma unroll
        for (int j = 0; j < 2; ++j)
            acc[i][j] = (fx4){0.f, 0.f, 0.f, 0.f};

    int kn = 64;
    auto kstep = [&](const unsigned short* Ac, const unsigned short* Bc,
                     unsigned short* Ad, unsigned short* Bd, bool pref) {
        if (pref) {
            #pragma unroll
            for (int g = 0; g < 2; ++g) {
                int rt = (wid * 2 + g) * 8;
                stage_rows8(A + (size_t)(m0 + rt) * K + kn, K, Ad + rt * 64, lane);
                stage_rows8(Bt + (size_t)(n0 + rt) * K + kn, K, Bd + rt * 64, lane);
            }
            kn += 64;
        }
        #pragma unroll
        for (int ks = 0; ks < 2; ++ks) {
            bh8 af[2], bfr[2];
            #pragma unroll
            for (int i = 0; i < 2; ++i) af[i] = frag_ld(Ac, wr + i * 16 + (lane & 15), ks * 4, lane);
            #pragma unroll
            for (int j = 0; j < 2; ++j) bfr[j] = frag_ld(Bc, wc + j * 16 + (lane & 15), ks * 4, lane);
            #pragma unroll
            for (int i = 0; i < 2; ++i)
                #pragma unroll
                for (int j = 0; j < 2; ++j)
                    acc[i][j] = __builtin_amdgcn_mfma_f32_16x16x32_bf16(af[i], bfr[j], acc[i][j], 0, 0, 0);
        }
        __syncthreads();
    };

    for (int t2 = 0; t2 < 6; ++t2) {             // K=768: 12 steps
        kstep(Ash[0], Bsh[0], Ash[1], Bsh[1], true);
        kstep(Ash[1], Bsh[1], Ash[0], Bsh[0], t2 < 5);
    }

    const int cc = lane & 15, g4 = (lane >> 4) * 4;
    #pragma unroll
    for (int j = 0; j < 2; ++j) {
        int col = n0 + wc + j * 16 + cc;
        float bv = bias[col];
        #pragma unroll
        for (int i = 0; i < 2; ++i) {
            #pragma unroll
            for (int r = 0; r < 4; ++r) {
                int row = m0 + wr + i * 16 + g4 + r;
                Cout[(size_t)row * N + col] = acc[i][j][r] + bv;
            }
        }
    }
}

// ---------------- flash attention: 2x2 wave split (q-half x kv-half), shift-0 softmax ----------------
// EXACT round-9/11/12 verified kernel (72.4 us, absmax 1.3e-4). Unchanged this round.
__global__ __launch_bounds__(256) void attn_fwd(const unsigned short* __restrict__ qkv,
                                                const unsigned short* __restrict__ vt,
                                                unsigned short* __restrict__ ao) {
    __shared__ __align__(16) char smem[40960];
    unsigned short* Qs  = (unsigned short*)smem;              // [64*64] 8 KB
    unsigned short* Ks0 = (unsigned short*)(smem + 8192);
    unsigned short* Ks1 = (unsigned short*)(smem + 16384);
    unsigned short* Vs0 = (unsigned short*)(smem + 24576);
    unsigned short* Vs1 = (unsigned short*)(smem + 32768);
    float* Of    = (float*)smem;            // epilogue overlay: [64 q][68] f32 = 17408 B
    float* l_lds = (float*)(smem + 17408);  // [64] f32 (both overlay dead K/Q buffers)

    const int h = blockIdx.y, q0 = blockIdx.x * 64;
    const int tid = threadIdx.x, wid = tid >> 6, lane = tid & 63;
    const int g = lane >> 4, qc = lane & 15, x = qc & 7;
    const int wq = wid >> 1, wk = wid & 1;

    const unsigned short* qg_ = qkv + (size_t)q0 * 2304 + h * 64;
    const unsigned short* kgb = qkv + 768 + h * 64;
    const unsigned short* vgb = vt + (size_t)h * 64 * 4096;

    #pragma unroll
    for (int gg = 0; gg < 2; ++gg) {
        int rt = (wid * 2 + gg) * 8;
        stage_rows8(qg_ + (size_t)rt * 2304, 2304, Qs + rt * 64, lane);
        stage_rows8(kgb + (size_t)rt * 2304, 2304, Ks0 + rt * 64, lane);
        stage_rows8(vgb + (size_t)rt * 4096, 4096, Vs0 + rt * 64, lane);
    }
    __syncthreads();

    bh8 qf[2][2];
    #pragma unroll
    for (int qg = 0; qg < 2; ++qg)
        #pragma unroll
        for (int kc = 0; kc < 2; ++kc)
            qf[qg][kc] = frag_ld(Qs, 32 * wq + 16 * qg + qc, 4 * kc, lane);

    int koff[2][2], voff[4];
    #pragma unroll
    for (int jm = 0; jm < 2; ++jm)
        #pragma unroll
        for (int kc = 0; kc < 2; ++kc)
            koff[jm][kc] = (32 * wk + 16 * jm + qc) * 64 + ((4 * kc + g) ^ x) * 8;
    #pragma unroll
    for (int dj = 0; dj < 4; ++dj)
        voff[dj] = (16 * dj + qc) * 64 + ((4 * wk + g) ^ x) * 8;

    float lrun[2] = {0.f, 0.f};
    fx4 oacP[4][2];
    #pragma unroll
    for (int dj = 0; dj < 4; ++dj)
        #pragma unroll
        for (int qg = 0; qg < 2; ++qg)
            oacP[dj][qg] = (fx4){0.f, 0.f, 0.f, 0.f};

    const unsigned short* knext = kgb + (size_t)64 * 2304;
    const unsigned short* vnext = vgb + 64;

    auto tile_step = [&](const unsigned short* Kc, const unsigned short* Vc,
                         unsigned short* Kd, unsigned short* Vd, bool pref) {
        if (pref) {
            #pragma unroll
            for (int gg = 0; gg < 2; ++gg) {
                int rt = (wid * 2 + gg) * 8;
                stage_rows8(knext + (size_t)rt * 2304, 2304, Kd + rt * 64, lane);
                stage_rows8(vnext + (size_t)rt * 4096, 4096, Vd + rt * 64, lane);
            }
            knext += (size_t)64 * 2304;
            vnext += 64;
        }

        bh8 kf[2][2];
        #pragma unroll
        for (int jm = 0; jm < 2; ++jm) {
            kf[jm][0] = *(const bh8*)(Kc + koff[jm][0]);
            kf[jm][1] = *(const bh8*)(Kc + koff[jm][1]);
        }
        fx4 sT[2][2];
        __builtin_amdgcn_s_setprio(1);
        #pragma unroll
        for (int jm = 0; jm < 2; ++jm)
            #pragma unroll
            for (int qg = 0; qg < 2; ++qg) {
                fx4 z = (fx4){0.f, 0.f, 0.f, 0.f};
                z = __builtin_amdgcn_mfma_f32_16x16x32_bf16(kf[jm][0], qf[qg][0], z, 0, 0, 0);
                z = __builtin_amdgcn_mfma_f32_16x16x32_bf16(kf[jm][1], qf[qg][1], z, 0, 0, 0);
                sT[jm][qg] = z;
            }
        __builtin_amdgcn_s_setprio(0);

        #pragma unroll
        for (int jm = 0; jm < 2; ++jm)
            #pragma unroll
            for (int qg = 0; qg < 2; ++qg) {
                sT[jm][qg][0] = __builtin_amdgcn_exp2f(sT[jm][qg][0]);
                sT[jm][qg][1] = __builtin_amdgcn_exp2f(sT[jm][qg][1]);
                sT[jm][qg][2] = __builtin_amdgcn_exp2f(sT[jm][qg][2]);
                sT[jm][qg][3] = __builtin_amdgcn_exp2f(sT[jm][qg][3]);
                lrun[qg] += (sT[jm][qg][0] + sT[jm][qg][1]) + (sT[jm][qg][2] + sT[jm][qg][3]);
            }

        bh8 vf[4];
        #pragma unroll
        for (int dj = 0; dj < 4; ++dj) vf[dj] = *(const bh8*)(Vc + voff[dj]);
        __builtin_amdgcn_s_setprio(1);
        #pragma unroll
        for (int qg = 0; qg < 2; ++qg) {
            bh8 pb = pack4(cvtpk_bf16(sT[0][qg][0], sT[0][qg][1]),
                           cvtpk_bf16(sT[0][qg][2], sT[0][qg][3]),
                           cvtpk_bf16(sT[1][qg][0], sT[1][qg][1]),
                           cvtpk_bf16(sT[1][qg][2], sT[1][qg][3]));
            #pragma unroll
            for (int dj = 0; dj < 4; ++dj)
                oacP[dj][qg] = __builtin_amdgcn_mfma_f32_16x16x32_bf16(vf[dj], pb, oacP[dj][qg], 0, 0, 0);
        }
        __builtin_amdgcn_s_setprio(0);
        __syncthreads();
    };

    for (int t2 = 0; t2 < 32; ++t2) {
        tile_step(Ks0, Vs0, Ks1, Vs1, true);
        tile_step(Ks1, Vs1, Ks0, Vs0, t2 < 31);
    }

    #pragma unroll
    for (int qg = 0; qg < 2; ++qg) {
        lrun[qg] += __shfl_xor(lrun[qg], 16);
        lrun[qg] += __shfl_xor(lrun[qg], 32);
    }
    if (wk == 1) {
        #pragma unroll
        for (int qg = 0; qg < 2; ++qg) {
            int q = 32 * wq + 16 * qg + qc;
            #pragma unroll
            for (int dj = 0; dj < 4; ++dj)
                *(fx4*)(Of + q * 68 + 16 * dj + 4 * g) = oacP[dj][qg];
            l_lds[q] = lrun[qg];
        }
    }
    __syncthreads();
    if (wk == 0) {
        #pragma unroll
        for (int qg = 0; qg < 2; ++qg) {
            int q = 32 * wq + 16 * qg + qc;
            float inv = 1.0f / (lrun[qg] + l_lds[q]);
            unsigned short* aop = ao + (size_t)(q0 + q) * 768 + h * 64;
            #pragma unroll
            for (int dj = 0; dj < 4; ++dj) {
                fx4 o = oacP[dj][qg];
                fx4 p = *(const fx4*)(Of + q * 68 + 16 * dj + 4 * g);
                int d0 = dj * 16 + 4 * g;
                *(unsigned int*)(aop + d0)     = cvtpk_bf16((o[0] + p[0]) * inv, (o[1] + p[1]) * inv);
                *(unsigned int*)(aop + d0 + 2) = cvtpk_bf16((o[2] + p[2]) * inv, (o[3] + p[3]) * inv);
            }
        }
    }
}

extern "C" void kernel_launch(void* const* d_in, const int* in_sizes, int n_in,
                              void* d_out, int out_size, void* d_ws, size_t ws_size,
                              hipStream_t stream) {
    const float* x     = (const float*)d_in[0];   // [4096,768]
    const float* w_qkv = (const float*)d_in[1];   // [768,2304]
    const float* b_qkv = (const float*)d_in[2];   // [2304]
    const float* w_out = (const float*)d_in[3];   // [768,768]
    const float* b_out = (const float*)d_in[4];   // [768]
    float* out = (float*)d_out;                   // [4096,768] fp32

    const int S = 4096, E = 768, E3 = 2304, H = 12;

    unsigned short* xb    = (unsigned short*)d_ws;          // S*E
    unsigned short* wqkvT = xb    + (size_t)S * E;          // E3*E
    unsigned short* woutT = wqkvT + (size_t)E3 * E;         // E*E
    unsigned short* qkvb  = woutT + (size_t)E * E;          // S*E3 (V third unused)
    unsigned short* vtp   = qkvb  + (size_t)S * E3;         // H*64*S
    unsigned short* ao    = vtp   + (size_t)H * 64 * S;     // S*E

    prep<<<dim3(3072 + 1728 + 576), 256, 0, stream>>>(x, xb, w_qkv, wqkvT, w_out, woutT);
    gemm_qkv<<<dim3(576), 256, 0, stream>>>(xb, wqkvT, b_qkv, qkvb, vtp);
    attn_fwd<<<dim3(S / 64, H), 256, 0, stream>>>(qkvb, vtp, ao);
    gemm64<<<dim3(E / 64, S / 64), 256, 0, stream>>>(ao, woutT, b_out, out, S, E, E);
}

// Round 14
// 116.169 us; speedup vs baseline: 1.1590x; 1.0066x over previous
//
#include <hip/hip_runtime.h>

typedef __attribute__((ext_vector_type(8))) short bh8;   // 8 x bf16 (4 VGPRs)
typedef __attribute__((ext_vector_type(4))) float fx4;   // 16x16 MFMA accumulator
typedef __attribute__((ext_vector_type(2))) float f32x2; // packed f32 pair (v_pk_add_f32)

// pack 2 f32 -> 2 bf16 in one u32 (RNE), low = a, high = b
__device__ __forceinline__ unsigned int cvtpk_bf16(float a, float b) {
    unsigned int r;
    asm("v_cvt_pk_bf16_f32 %0, %1, %2" : "=v"(r) : "v"(a), "v"(b));
    return r;
}
// single f32 -> bf16 (RNE) in 1 VALU op: low half of cvtpk
__device__ __forceinline__ unsigned short bf1(float a) {
    return (unsigned short)cvtpk_bf16(a, a);
}

__device__ __forceinline__ bh8 pack4(unsigned int a, unsigned int b,
                                     unsigned int c, unsigned int d) {
    union { unsigned int u[4]; bh8 h; } z;
    z.u[0] = a; z.u[1] = b; z.u[2] = c; z.u[3] = d;
    return z.h;
}

// Stage 8 rows x 64 bf16 cols into LDS (linear dest) via global_load_lds width=16.
// Global source chunk is XOR-swizzled by row&7 (rule #21: swizzle source + read).
__device__ __forceinline__ void stage_rows8(const unsigned short* g, long ldg,
                                            unsigned short* lds, int lane) {
    int r8 = lane >> 3;
    int gc = (lane & 7) ^ r8;
    __builtin_amdgcn_global_load_lds(
        (const __attribute__((address_space(1))) void*)(g + (long)r8 * ldg + gc * 8),
        (__attribute__((address_space(3))) void*)lds, 16, 0, 0);
}

// 16x16x32 fragment read from a swizzled [rows][64] tile (VERIFIED in passing gemms):
// logical k-chunk = kchunk + (lane>>4), stored at chunk^(row&7).
__device__ __forceinline__ bh8 frag_ld(const unsigned short* t, int row, int kchunk, int lane) {
    int ch = (kchunk + (lane >> 4)) ^ (row & 7);
    return *(const bh8*)(t + row * 64 + ch * 8);
}

// ---------------- merged prep: castbf (x->bf16) + transW(w_qkv) + transW(w_out) ----------------
__global__ __launch_bounds__(256) void prep(const float* __restrict__ x,
                                            unsigned short* __restrict__ xb,
                                            const float* __restrict__ w_qkv,
                                            unsigned short* __restrict__ wqkvT,
                                            const float* __restrict__ w_out,
                                            unsigned short* __restrict__ woutT) {
    __shared__ float t[32][33];
    const int bid = blockIdx.x;
    if (bid < 3072) {                       // castbf: 4096*768 elems / 1024 per block
        int i = (bid * 256 + threadIdx.x) * 4;
        float4 v = *(const float4*)(x + i);
        *(uint2*)(xb + i) = make_uint2(cvtpk_bf16(v.x, v.y), cvtpk_bf16(v.z, v.w));
        return;
    }
    const float* W; unsigned short* Wt; int N, xid;
    if (bid < 3072 + 1728) { W = w_qkv; Wt = wqkvT; N = 2304; xid = bid - 3072; }
    else                   { W = w_out; Wt = woutT; N = 768;  xid = bid - 4800; }
    const int K = 768, nb = N / 32;
    const int n0 = (xid % nb) * 32, k0 = (xid / nb) * 32;
    const int tx = threadIdx.x & 31, ty = threadIdx.x >> 5;
    #pragma unroll
    for (int r = ty; r < 32; r += 8)
        t[r][tx] = W[(size_t)(k0 + r) * N + n0 + tx];
    __syncthreads();
    #pragma unroll
    for (int r = ty; r < 32; r += 8)
        Wt[(size_t)(n0 + r) * K + k0 + tx] = bf1(t[tx][r]);
}

// ---------------- QKV GEMM, 128x128 tile, dbuf single-barrier, XCD-swizzled ----------------
// Schedule = verified r12 dbuf kstep. Q cols [0,768) pre-scaled by log2(e)/8 (block-uniform).
// V cols [1536,2304): padded-LDS transpose -> vt with the verified pos() permutation
// pos(32a+16b+4g+r)=32a+8g+4b+r per 64-s block; inverse base sb=(y&32)+((y&24)>>1).
__global__ __launch_bounds__(256) void gemm_qkv(const unsigned short* __restrict__ A,
                                                const unsigned short* __restrict__ Bt,
                                                const float* __restrict__ bias,
                                                unsigned short* __restrict__ Cout,
                                                unsigned short* __restrict__ vt) {
    const int N = 2304, K = 768;
    __shared__ __align__(16) char smem[65536];
    unsigned short* Ash0 = (unsigned short*)smem;             // 16 KB each
    unsigned short* Ash1 = (unsigned short*)(smem + 16384);
    unsigned short* Bsh0 = (unsigned short*)(smem + 32768);
    unsigned short* Bsh1 = (unsigned short*)(smem + 49152);
    unsigned short* Tsc  = (unsigned short*)smem;             // V scratch [128][132] overlay

    const int bid = blockIdx.x;
    const int swz = (bid & 7) * 72 + (bid >> 3);
    const int m0 = (swz / 18) * 128, n0 = (swz % 18) * 128;
    const int tid = threadIdx.x, wid = tid >> 6, lane = tid & 63;
    const int wr = (wid >> 1) * 64, wc = (wid & 1) * 64;

    // stage K-step 0
    #pragma unroll
    for (int g = 0; g < 4; ++g) {
        int rt = (wid * 4 + g) * 8;
        stage_rows8(A + (size_t)(m0 + rt) * K, K, Ash0 + rt * 64, lane);
        stage_rows8(Bt + (size_t)(n0 + rt) * K, K, Bsh0 + rt * 64, lane);
    }
    __syncthreads();

    fx4 acc[4][4];
    #pragma unroll
    for (int i = 0; i < 4; ++i)
        #pragma unroll
        for (int j = 0; j < 4; ++j)
            acc[i][j] = (fx4){0.f, 0.f, 0.f, 0.f};

    int kn = 64;
    auto kstep = [&](const unsigned short* Ac, const unsigned short* Bc,
                     unsigned short* Ad, unsigned short* Bd, bool pref) {
        if (pref) {  // prefetch next K-slab (drained at the loop-end barrier)
            #pragma unroll
            for (int g = 0; g < 4; ++g) {
                int rt = (wid * 4 + g) * 8;
                stage_rows8(A + (size_t)(m0 + rt) * K + kn, K, Ad + rt * 64, lane);
                stage_rows8(Bt + (size_t)(n0 + rt) * K + kn, K, Bd + rt * 64, lane);
            }
            kn += 64;
        }
        #pragma unroll
        for (int ks = 0; ks < 2; ++ks) {
            bh8 af[4], bfr[4];
            #pragma unroll
            for (int i = 0; i < 4; ++i) af[i] = frag_ld(Ac, wr + i * 16 + (lane & 15), ks * 4, lane);
            #pragma unroll
            for (int j = 0; j < 4; ++j) bfr[j] = frag_ld(Bc, wc + j * 16 + (lane & 15), ks * 4, lane);
            #pragma unroll
            for (int i = 0; i < 4; ++i)
                #pragma unroll
                for (int j = 0; j < 4; ++j)
                    acc[i][j] = __builtin_amdgcn_mfma_f32_16x16x32_bf16(af[i], bfr[j], acc[i][j], 0, 0, 0);
        }
        __syncthreads();
    };

    for (int t2 = 0; t2 < 6; ++t2) {             // 12 K-steps of 64
        kstep(Ash0, Bsh0, Ash1, Bsh1, true);
        kstep(Ash1, Bsh1, Ash0, Bsh0, t2 < 5);
    }

    const int cc = lane & 15, g4 = (lane >> 4) * 4;
    if (n0 < 1536) {
        // Q/K blocks: plain store to qkvb. Scale is block-uniform (n0 is 128-aligned,
        // so the 768 boundary never splits a block).
        const float sc = (n0 < 768) ? 0.18033688011112042f : 1.0f;
        #pragma unroll
        for (int j = 0; j < 4; ++j) {
            int col = n0 + wc + j * 16 + cc;
            float bv = bias[col];
            #pragma unroll
            for (int i = 0; i < 4; ++i) {
                #pragma unroll
                for (int r = 0; r < 4; ++r) {
                    int row = m0 + wr + i * 16 + g4 + r;
                    Cout[(size_t)row * N + col] = bf1((acc[i][j][r] + bv) * sc);
                }
            }
        }
    } else {
        // V block: acc -> Tsc[d][s] (stride 132 breaks write conflicts), then permuted
        // coalesced row writes to vt (fused transV; verified r12/r13 path).
        #pragma unroll
        for (int j = 0; j < 4; ++j) {
            int dloc = wc + j * 16 + cc;
            float bv = bias[n0 + dloc];
            #pragma unroll
            for (int i = 0; i < 4; ++i) {
                int sloc = wr + i * 16 + g4;
                unsigned int u0 = cvtpk_bf16(acc[i][j][0] + bv, acc[i][j][1] + bv);
                unsigned int u1 = cvtpk_bf16(acc[i][j][2] + bv, acc[i][j][3] + bv);
                *(uint2*)(Tsc + dloc * 132 + sloc) = make_uint2(u0, u1);
            }
        }
        __syncthreads();
        const int d = tid >> 1, bblk = tid & 1;
        const unsigned short* srow = Tsc + d * 132 + bblk * 64;
        unsigned short* dst = vt + (size_t)(n0 - 1536 + d) * 4096 + m0 + bblk * 64;
        #pragma unroll
        for (int k = 0; k < 8; ++k) {
            int y = 8 * k;
            int sb = (y & 32) + ((y & 24) >> 1);      // inverse-perm base; +16 for b=1
            uint2 lo = *(const uint2*)(srow + sb);
            uint2 hi = *(const uint2*)(srow + sb + 16);
            *(uint4*)(dst + 8 * k) = make_uint4(lo.x, lo.y, hi.x, hi.y);
        }
    }
}

// ---------------- GEMM 64x64 (output projection), single-barrier double-buffered ----------------
__global__ __launch_bounds__(256) void gemm64(const unsigned short* __restrict__ A,
                                              const unsigned short* __restrict__ Bt,
                                              const float* __restrict__ bias,
                                              float* __restrict__ Cout,
                                              int M, int N, int K) {
    __shared__ __align__(16) unsigned short Ash[2][64 * 64];
    __shared__ __align__(16) unsigned short Bsh[2][64 * 64];
    const int m0 = blockIdx.y * 64, n0 = blockIdx.x * 64;
    const int tid = threadIdx.x, wid = tid >> 6, lane = tid & 63;
    const int wr = (wid >> 1) * 32, wc = (wid & 1) * 32;

    #pragma unroll
    for (int g = 0; g < 2; ++g) {
        int rt = (wid * 2 + g) * 8;
        stage_rows8(A + (size_t)(m0 + rt) * K, K, Ash[0] + rt * 64, lane);
        stage_rows8(Bt + (size_t)(n0 + rt) * K, K, Bsh[0] + rt * 64, lane);
    }
    __syncthreads();

    fx4 acc[2][2];
    #pragma unroll
    for (int i = 0; i < 2; ++i)
        #pragma unroll
        for (int j = 0; j < 2; ++j)
            acc[i][j] = (fx4){0.f, 0.f, 0.f, 0.f};

    int kn = 64;
    auto kstep = [&](const unsigned short* Ac, const unsigned short* Bc,
                     unsigned short* Ad, unsigned short* Bd, bool pref) {
        if (pref) {
            #pragma unroll
            for (int g = 0; g < 2; ++g) {
                int rt = (wid * 2 + g) * 8;
                stage_rows8(A + (size_t)(m0 + rt) * K + kn, K, Ad + rt * 64, lane);
                stage_rows8(Bt + (size_t)(n0 + rt) * K + kn, K, Bd + rt * 64, lane);
            }
            kn += 64;
        }
        #pragma unroll
        for (int ks = 0; ks < 2; ++ks) {
            bh8 af[2], bfr[2];
            #pragma unroll
            for (int i = 0; i < 2; ++i) af[i] = frag_ld(Ac, wr + i * 16 + (lane & 15), ks * 4, lane);
            #pragma unroll
            for (int j = 0; j < 2; ++j) bfr[j] = frag_ld(Bc, wc + j * 16 + (lane & 15), ks * 4, lane);
            #pragma unroll
            for (int i = 0; i < 2; ++i)
                #pragma unroll
                for (int j = 0; j < 2; ++j)
                    acc[i][j] = __builtin_amdgcn_mfma_f32_16x16x32_bf16(af[i], bfr[j], acc[i][j], 0, 0, 0);
        }
        __syncthreads();
    };

    for (int t2 = 0; t2 < 6; ++t2) {             // K=768: 12 steps
        kstep(Ash[0], Bsh[0], Ash[1], Bsh[1], true);
        kstep(Ash[1], Bsh[1], Ash[0], Bsh[0], t2 < 5);
    }

    const int cc = lane & 15, g4 = (lane >> 4) * 4;
    #pragma unroll
    for (int j = 0; j < 2; ++j) {
        int col = n0 + wc + j * 16 + cc;
        float bv = bias[col];
        #pragma unroll
        for (int i = 0; i < 2; ++i) {
            #pragma unroll
            for (int r = 0; r < 4; ++r) {
                int row = m0 + wr + i * 16 + g4 + r;
                Cout[(size_t)row * N + col] = acc[i][j][r] + bv;
            }
        }
    }
}

// ---------------- flash attention: 2x2 wave split (q-half x kv-half), shift-0 softmax ----------------
// Round-9/11/12/13 verified kernel; ONLY change this round: lrun accumulated as a
// packed float2 (element pairs of the MFMA quad are aligned register pairs ->
// compiler can emit v_pk_add_f32), folded to scalar in the epilogue.
__global__ __launch_bounds__(256) void attn_fwd(const unsigned short* __restrict__ qkv,
                                                const unsigned short* __restrict__ vt,
                                                unsigned short* __restrict__ ao) {
    __shared__ __align__(16) char smem[40960];
    unsigned short* Qs  = (unsigned short*)smem;              // [64*64] 8 KB
    unsigned short* Ks0 = (unsigned short*)(smem + 8192);
    unsigned short* Ks1 = (unsigned short*)(smem + 16384);
    unsigned short* Vs0 = (unsigned short*)(smem + 24576);
    unsigned short* Vs1 = (unsigned short*)(smem + 32768);
    float* Of    = (float*)smem;            // epilogue overlay: [64 q][68] f32 = 17408 B
    float* l_lds = (float*)(smem + 17408);  // [64] f32 (both overlay dead K/Q buffers)

    const int h = blockIdx.y, q0 = blockIdx.x * 64;
    const int tid = threadIdx.x, wid = tid >> 6, lane = tid & 63;
    const int g = lane >> 4, qc = lane & 15, x = qc & 7;
    const int wq = wid >> 1, wk = wid & 1;

    const unsigned short* qg_ = qkv + (size_t)q0 * 2304 + h * 64;
    const unsigned short* kgb = qkv + 768 + h * 64;
    const unsigned short* vgb = vt + (size_t)h * 64 * 4096;

    #pragma unroll
    for (int gg = 0; gg < 2; ++gg) {
        int rt = (wid * 2 + gg) * 8;
        stage_rows8(qg_ + (size_t)rt * 2304, 2304, Qs + rt * 64, lane);
        stage_rows8(kgb + (size_t)rt * 2304, 2304, Ks0 + rt * 64, lane);
        stage_rows8(vgb + (size_t)rt * 4096, 4096, Vs0 + rt * 64, lane);
    }
    __syncthreads();

    bh8 qf[2][2];
    #pragma unroll
    for (int qg = 0; qg < 2; ++qg)
        #pragma unroll
        for (int kc = 0; kc < 2; ++kc)
            qf[qg][kc] = frag_ld(Qs, 32 * wq + 16 * qg + qc, 4 * kc, lane);

    int koff[2][2], voff[4];
    #pragma unroll
    for (int jm = 0; jm < 2; ++jm)
        #pragma unroll
        for (int kc = 0; kc < 2; ++kc)
            koff[jm][kc] = (32 * wk + 16 * jm + qc) * 64 + ((4 * kc + g) ^ x) * 8;
    #pragma unroll
    for (int dj = 0; dj < 4; ++dj)
        voff[dj] = (16 * dj + qc) * 64 + ((4 * wk + g) ^ x) * 8;

    f32x2 l2[2] = {(f32x2){0.f, 0.f}, (f32x2){0.f, 0.f}};
    fx4 oacP[4][2];
    #pragma unroll
    for (int dj = 0; dj < 4; ++dj)
        #pragma unroll
        for (int qg = 0; qg < 2; ++qg)
            oacP[dj][qg] = (fx4){0.f, 0.f, 0.f, 0.f};

    const unsigned short* knext = kgb + (size_t)64 * 2304;
    const unsigned short* vnext = vgb + 64;

    auto tile_step = [&](const unsigned short* Kc, const unsigned short* Vc,
                         unsigned short* Kd, unsigned short* Vd, bool pref) {
        if (pref) {
            #pragma unroll
            for (int gg = 0; gg < 2; ++gg) {
                int rt = (wid * 2 + gg) * 8;
                stage_rows8(knext + (size_t)rt * 2304, 2304, Kd + rt * 64, lane);
                stage_rows8(vnext + (size_t)rt * 4096, 4096, Vd + rt * 64, lane);
            }
            knext += (size_t)64 * 2304;
            vnext += 64;
        }

        bh8 kf[2][2];
        #pragma unroll
        for (int jm = 0; jm < 2; ++jm) {
            kf[jm][0] = *(const bh8*)(Kc + koff[jm][0]);
            kf[jm][1] = *(const bh8*)(Kc + koff[jm][1]);
        }
        fx4 sT[2][2];
        __builtin_amdgcn_s_setprio(1);
        #pragma unroll
        for (int jm = 0; jm < 2; ++jm)
            #pragma unroll
            for (int qg = 0; qg < 2; ++qg) {
                fx4 z = (fx4){0.f, 0.f, 0.f, 0.f};
                z = __builtin_amdgcn_mfma_f32_16x16x32_bf16(kf[jm][0], qf[qg][0], z, 0, 0, 0);
                z = __builtin_amdgcn_mfma_f32_16x16x32_bf16(kf[jm][1], qf[qg][1], z, 0, 0, 0);
                sT[jm][qg] = z;
            }
        __builtin_amdgcn_s_setprio(0);

        #pragma unroll
        for (int jm = 0; jm < 2; ++jm)
            #pragma unroll
            for (int qg = 0; qg < 2; ++qg) {
                sT[jm][qg][0] = __builtin_amdgcn_exp2f(sT[jm][qg][0]);
                sT[jm][qg][1] = __builtin_amdgcn_exp2f(sT[jm][qg][1]);
                sT[jm][qg][2] = __builtin_amdgcn_exp2f(sT[jm][qg][2]);
                sT[jm][qg][3] = __builtin_amdgcn_exp2f(sT[jm][qg][3]);
                l2[qg] += __builtin_shufflevector(sT[jm][qg], sT[jm][qg], 0, 1)
                        + __builtin_shufflevector(sT[jm][qg], sT[jm][qg], 2, 3);
            }

        bh8 vf[4];
        #pragma unroll
        for (int dj = 0; dj < 4; ++dj) vf[dj] = *(const bh8*)(Vc + voff[dj]);
        __builtin_amdgcn_s_setprio(1);
        #pragma unroll
        for (int qg = 0; qg < 2; ++qg) {
            bh8 pb = pack4(cvtpk_bf16(sT[0][qg][0], sT[0][qg][1]),
                           cvtpk_bf16(sT[0][qg][2], sT[0][qg][3]),
                           cvtpk_bf16(sT[1][qg][0], sT[1][qg][1]),
                           cvtpk_bf16(sT[1][qg][2], sT[1][qg][3]));
            #pragma unroll
            for (int dj = 0; dj < 4; ++dj)
                oacP[dj][qg] = __builtin_amdgcn_mfma_f32_16x16x32_bf16(vf[dj], pb, oacP[dj][qg], 0, 0, 0);
        }
        __builtin_amdgcn_s_setprio(0);
        __syncthreads();
    };

    for (int t2 = 0; t2 < 32; ++t2) {
        tile_step(Ks0, Vs0, Ks1, Vs1, true);
        tile_step(Ks1, Vs1, Ks0, Vs0, t2 < 31);
    }

    float lrun[2];
    #pragma unroll
    for (int qg = 0; qg < 2; ++qg) {
        lrun[qg] = l2[qg][0] + l2[qg][1];
        lrun[qg] += __shfl_xor(lrun[qg], 16);
        lrun[qg] += __shfl_xor(lrun[qg], 32);
    }
    if (wk == 1) {
        #pragma unroll
        for (int qg = 0; qg < 2; ++qg) {
            int q = 32 * wq + 16 * qg + qc;
            #pragma unroll
            for (int dj = 0; dj < 4; ++dj)
                *(fx4*)(Of + q * 68 + 16 * dj + 4 * g) = oacP[dj][qg];
            l_lds[q] = lrun[qg];
        }
    }
    __syncthreads();
    if (wk == 0) {
        #pragma unroll
        for (int qg = 0; qg < 2; ++qg) {
            int q = 32 * wq + 16 * qg + qc;
            float inv = 1.0f / (lrun[qg] + l_lds[q]);
            unsigned short* aop = ao + (size_t)(q0 + q) * 768 + h * 64;
            #pragma unroll
            for (int dj = 0; dj < 4; ++dj) {
                fx4 o = oacP[dj][qg];
                fx4 p = *(const fx4*)(Of + q * 68 + 16 * dj + 4 * g);
                int d0 = dj * 16 + 4 * g;
                *(unsigned int*)(aop + d0)     = cvtpk_bf16((o[0] + p[0]) * inv, (o[1] + p[1]) * inv);
                *(unsigned int*)(aop + d0 + 2) = cvtpk_bf16((o[2] + p[2]) * inv, (o[3] + p[3]) * inv);
            }
        }
    }
}

extern "C" void kernel_launch(void* const* d_in, const int* in_sizes, int n_in,
                              void* d_out, int out_size, void* d_ws, size_t ws_size,
                              hipStream_t stream) {
    const float* x     = (const float*)d_in[0];   // [4096,768]
    const float* w_qkv = (const float*)d_in[1];   // [768,2304]
    const float* b_qkv = (const float*)d_in[2];   // [2304]
    const float* w_out = (const float*)d_in[3];   // [768,768]
    const float* b_out = (const float*)d_in[4];   // [768]
    float* out = (float*)d_out;                   // [4096,768] fp32

    const int S = 4096, E = 768, E3 = 2304, H = 12;

    unsigned short* xb    = (unsigned short*)d_ws;          // S*E
    unsigned short* wqkvT = xb    + (size_t)S * E;          // E3*E
    unsigned short* woutT = wqkvT + (size_t)E3 * E;         // E*E
    unsigned short* qkvb  = woutT + (size_t)E * E;          // S*E3 (V third unused)
    unsigned short* vtp   = qkvb  + (size_t)S * E3;         // H*64*S
    unsigned short* ao    = vtp   + (size_t)H * 64 * S;     // S*E

    prep<<<dim3(3072 + 1728 + 576), 256, 0, stream>>>(x, xb, w_qkv, wqkvT, w_out, woutT);
    gemm_qkv<<<dim3(576), 256, 0, stream>>>(xb, wqkvT, b_qkv, qkvb, vtp);
    attn_fwd<<<dim3(S / 64, H), 256, 0, stream>>>(qkvb, vtp, ao);
    gemm64<<<dim3(E / 64, S / 64), 256, 0, stream>>>(ao, woutT, b_out, out, S, E, E);
}

// Round 15
// 114.563 us; speedup vs baseline: 1.1753x; 1.0140x over previous
//
#include <hip/hip_runtime.h>

typedef __attribute__((ext_vector_type(8))) short bh8;   // 8 x bf16 (4 VGPRs)
typedef __attribute__((ext_vector_type(4))) float fx4;   // 16x16 MFMA accumulator
typedef __attribute__((ext_vector_type(2))) float f32x2; // packed f32 pair (v_pk_add_f32)

// pack 2 f32 -> 2 bf16 in one u32 (RNE), low = a, high = b
__device__ __forceinline__ unsigned int cvtpk_bf16(float a, float b) {
    unsigned int r;
    asm("v_cvt_pk_bf16_f32 %0, %1, %2" : "=v"(r) : "v"(a), "v"(b));
    return r;
}
// single f32 -> bf16 (RNE) in 1 VALU op: low half of cvtpk
__device__ __forceinline__ unsigned short bf1(float a) {
    return (unsigned short)cvtpk_bf16(a, a);
}

__device__ __forceinline__ bh8 pack4(unsigned int a, unsigned int b,
                                     unsigned int c, unsigned int d) {
    union { unsigned int u[4]; bh8 h; } z;
    z.u[0] = a; z.u[1] = b; z.u[2] = c; z.u[3] = d;
    return z.h;
}

// Stage 8 rows x 64 bf16 cols into LDS (linear dest) via global_load_lds width=16.
// Global source chunk is XOR-swizzled by row&7 (rule #21: swizzle source + read).
__device__ __forceinline__ void stage_rows8(const unsigned short* g, long ldg,
                                            unsigned short* lds, int lane) {
    int r8 = lane >> 3;
    int gc = (lane & 7) ^ r8;
    __builtin_amdgcn_global_load_lds(
        (const __attribute__((address_space(1))) void*)(g + (long)r8 * ldg + gc * 8),
        (__attribute__((address_space(3))) void*)lds, 16, 0, 0);
}

// 16x16x32 fragment read from a swizzled [rows][64] tile (VERIFIED in passing gemms):
// logical k-chunk = kchunk + (lane>>4), stored at chunk^(row&7).
__device__ __forceinline__ bh8 frag_ld(const unsigned short* t, int row, int kchunk, int lane) {
    int ch = (kchunk + (lane >> 4)) ^ (row & 7);
    return *(const bh8*)(t + row * 64 + ch * 8);
}

// ---------------- merged prep: castbf (x->bf16) + transW(w_qkv) + transW(w_out) ----------------
__global__ __launch_bounds__(256) void prep(const float* __restrict__ x,
                                            unsigned short* __restrict__ xb,
                                            const float* __restrict__ w_qkv,
                                            unsigned short* __restrict__ wqkvT,
                                            const float* __restrict__ w_out,
                                            unsigned short* __restrict__ woutT) {
    __shared__ float t[32][33];
    const int bid = blockIdx.x;
    if (bid < 3072) {                       // castbf: 4096*768 elems / 1024 per block
        int i = (bid * 256 + threadIdx.x) * 4;
        float4 v = *(const float4*)(x + i);
        *(uint2*)(xb + i) = make_uint2(cvtpk_bf16(v.x, v.y), cvtpk_bf16(v.z, v.w));
        return;
    }
    const float* W; unsigned short* Wt; int N, xid;
    if (bid < 3072 + 1728) { W = w_qkv; Wt = wqkvT; N = 2304; xid = bid - 3072; }
    else                   { W = w_out; Wt = woutT; N = 768;  xid = bid - 4800; }
    const int K = 768, nb = N / 32;
    const int n0 = (xid % nb) * 32, k0 = (xid / nb) * 32;
    const int tx = threadIdx.x & 31, ty = threadIdx.x >> 5;
    #pragma unroll
    for (int r = ty; r < 32; r += 8)
        t[r][tx] = W[(size_t)(k0 + r) * N + n0 + tx];
    __syncthreads();
    #pragma unroll
    for (int r = ty; r < 32; r += 8)
        Wt[(size_t)(n0 + r) * K + k0 + tx] = bf1(t[tx][r]);
}

// ---------------- QKV GEMM, 64x128 tile (r12-proven geometry), dbuf, XCD-swizzled ----------------
// 1152 blocks = 4.5/CU (tail ~11%), 48 KB LDS -> 3 co-resident blocks/CU.
// XCD swizzle: 1152%8==0, 144 blocks/XCD = 8 A-slabs + B panel ~ 4.3 MB ~ L2.
// Q cols [0,768) pre-scaled by log2(e)/8 (block-uniform: n0 is 128-aligned).
// V cols [1536,2304): padded-LDS transpose -> vt with the verified pos() permutation
// pos(32a+16b+4g+r)=32a+8g+4b+r; inverse base sb=(y&32)+((y&24)>>1) (+16 for b=1).
__global__ __launch_bounds__(256) void gemm_qkv(const unsigned short* __restrict__ A,
                                                const unsigned short* __restrict__ Bt,
                                                const float* __restrict__ bias,
                                                unsigned short* __restrict__ Cout,
                                                unsigned short* __restrict__ vt) {
    const int N = 2304, K = 768;
    __shared__ __align__(16) char smem[49152];
    unsigned short* Ash0 = (unsigned short*)smem;             // 8 KB each
    unsigned short* Ash1 = (unsigned short*)(smem + 8192);
    unsigned short* Bsh0 = (unsigned short*)(smem + 16384);   // 16 KB each
    unsigned short* Bsh1 = (unsigned short*)(smem + 32768);
    unsigned short* Tsc  = (unsigned short*)smem;             // V scratch [128][68] = 17.4 KB overlay

    const int bid = blockIdx.x;
    const int swz = (bid & 7) * 144 + (bid >> 3);
    const int m0 = (swz / 18) * 64, n0 = (swz % 18) * 128;
    const int tid = threadIdx.x, wid = tid >> 6, lane = tid & 63;
    const int wr = (wid >> 1) * 32, wc = (wid & 1) * 64;

    // stage K-step 0
    #pragma unroll
    for (int g = 0; g < 2; ++g) {
        int rt = (wid * 2 + g) * 8;
        stage_rows8(A + (size_t)(m0 + rt) * K, K, Ash0 + rt * 64, lane);
    }
    #pragma unroll
    for (int g = 0; g < 4; ++g) {
        int rt = (wid * 4 + g) * 8;
        stage_rows8(Bt + (size_t)(n0 + rt) * K, K, Bsh0 + rt * 64, lane);
    }
    __syncthreads();

    fx4 acc[2][4];
    #pragma unroll
    for (int i = 0; i < 2; ++i)
        #pragma unroll
        for (int j = 0; j < 4; ++j)
            acc[i][j] = (fx4){0.f, 0.f, 0.f, 0.f};

    int kn = 64;
    auto kstep = [&](const unsigned short* Ac, const unsigned short* Bc,
                     unsigned short* Ad, unsigned short* Bd, bool pref) {
        if (pref) {  // prefetch next K-slab (drained at the loop-end barrier)
            #pragma unroll
            for (int g = 0; g < 2; ++g) {
                int rt = (wid * 2 + g) * 8;
                stage_rows8(A + (size_t)(m0 + rt) * K + kn, K, Ad + rt * 64, lane);
            }
            #pragma unroll
            for (int g = 0; g < 4; ++g) {
                int rt = (wid * 4 + g) * 8;
                stage_rows8(Bt + (size_t)(n0 + rt) * K + kn, K, Bd + rt * 64, lane);
            }
            kn += 64;
        }
        #pragma unroll
        for (int ks = 0; ks < 2; ++ks) {
            bh8 af[2], bfr[4];
            #pragma unroll
            for (int i = 0; i < 2; ++i) af[i] = frag_ld(Ac, wr + i * 16 + (lane & 15), ks * 4, lane);
            #pragma unroll
            for (int j = 0; j < 4; ++j) bfr[j] = frag_ld(Bc, wc + j * 16 + (lane & 15), ks * 4, lane);
            #pragma unroll
            for (int i = 0; i < 2; ++i)
                #pragma unroll
                for (int j = 0; j < 4; ++j)
                    acc[i][j] = __builtin_amdgcn_mfma_f32_16x16x32_bf16(af[i], bfr[j], acc[i][j], 0, 0, 0);
        }
        __syncthreads();
    };

    for (int t2 = 0; t2 < 6; ++t2) {             // 12 K-steps of 64
        kstep(Ash0, Bsh0, Ash1, Bsh1, true);
        kstep(Ash1, Bsh1, Ash0, Bsh0, t2 < 5);
    }

    const int cc = lane & 15, g4 = (lane >> 4) * 4;
    if (n0 < 1536) {
        // Q/K blocks: plain store (scale block-uniform: 768 boundary never splits a block)
        const float sc = (n0 < 768) ? 0.18033688011112042f : 1.0f;
        #pragma unroll
        for (int j = 0; j < 4; ++j) {
            int col = n0 + wc + j * 16 + cc;
            float bv = bias[col];
            #pragma unroll
            for (int i = 0; i < 2; ++i) {
                #pragma unroll
                for (int r = 0; r < 4; ++r) {
                    int row = m0 + wr + i * 16 + g4 + r;
                    Cout[(size_t)row * N + col] = bf1((acc[i][j][r] + bv) * sc);
                }
            }
        }
    } else {
        // V block: acc -> Tsc[d][s] (stride 68 breaks write conflicts), then permuted
        // coalesced row writes to vt (fused transV; r12-HW-verified form).
        #pragma unroll
        for (int j = 0; j < 4; ++j) {
            int dloc = wc + j * 16 + cc;
            float bv = bias[n0 + dloc];
            #pragma unroll
            for (int i = 0; i < 2; ++i) {
                int sloc = wr + i * 16 + g4;
                unsigned int u0 = cvtpk_bf16(acc[i][j][0] + bv, acc[i][j][1] + bv);
                unsigned int u1 = cvtpk_bf16(acc[i][j][2] + bv, acc[i][j][3] + bv);
                *(uint2*)(Tsc + dloc * 68 + sloc) = make_uint2(u0, u1);
            }
        }
        __syncthreads();
        const int d = tid >> 1, hf = (tid & 1) << 5;
        const unsigned short* srow = Tsc + d * 68;
        unsigned short* dst = vt + (size_t)(n0 - 1536 + d) * 4096 + m0 + hf;
        #pragma unroll
        for (int k = 0; k < 4; ++k) {
            int y = hf + 8 * k;
            int sb = (y & 32) + ((y & 24) >> 1);      // inverse-perm base; +16 for b=1
            uint2 lo = *(const uint2*)(srow + sb);
            uint2 hi = *(const uint2*)(srow + sb + 16);
            *(uint4*)(dst + 8 * k) = make_uint4(lo.x, lo.y, hi.x, hi.y);
        }
    }
}

// ---------------- GEMM 64x64 (output projection), single-barrier double-buffered ----------------
__global__ __launch_bounds__(256) void gemm64(const unsigned short* __restrict__ A,
                                              const unsigned short* __restrict__ Bt,
                                              const float* __restrict__ bias,
                                              float* __restrict__ Cout,
                                              int M, int N, int K) {
    __shared__ __align__(16) unsigned short Ash[2][64 * 64];
    __shared__ __align__(16) unsigned short Bsh[2][64 * 64];
    const int m0 = blockIdx.y * 64, n0 = blockIdx.x * 64;
    const int tid = threadIdx.x, wid = tid >> 6, lane = tid & 63;
    const int wr = (wid >> 1) * 32, wc = (wid & 1) * 32;

    #pragma unroll
    for (int g = 0; g < 2; ++g) {
        int rt = (wid * 2 + g) * 8;
        stage_rows8(A + (size_t)(m0 + rt) * K, K, Ash[0] + rt * 64, lane);
        stage_rows8(Bt + (size_t)(n0 + rt) * K, K, Bsh[0] + rt * 64, lane);
    }
    __syncthreads();

    fx4 acc[2][2];
    #pragma unroll
    for (int i = 0; i < 2; ++i)
        #pragma unroll
        for (int j = 0; j < 2; ++j)
            acc[i][j] = (fx4){0.f, 0.f, 0.f, 0.f};

    int kn = 64;
    auto kstep = [&](const unsigned short* Ac, const unsigned short* Bc,
                     unsigned short* Ad, unsigned short* Bd, bool pref) {
        if (pref) {
            #pragma unroll
            for (int g = 0; g < 2; ++g) {
                int rt = (wid * 2 + g) * 8;
                stage_rows8(A + (size_t)(m0 + rt) * K + kn, K, Ad + rt * 64, lane);
                stage_rows8(Bt + (size_t)(n0 + rt) * K + kn, K, Bd + rt * 64, lane);
            }
            kn += 64;
        }
        #pragma unroll
        for (int ks = 0; ks < 2; ++ks) {
            bh8 af[2], bfr[2];
            #pragma unroll
            for (int i = 0; i < 2; ++i) af[i] = frag_ld(Ac, wr + i * 16 + (lane & 15), ks * 4, lane);
            #pragma unroll
            for (int j = 0; j < 2; ++j) bfr[j] = frag_ld(Bc, wc + j * 16 + (lane & 15), ks * 4, lane);
            #pragma unroll
            for (int i = 0; i < 2; ++i)
                #pragma unroll
                for (int j = 0; j < 2; ++j)
                    acc[i][j] = __builtin_amdgcn_mfma_f32_16x16x32_bf16(af[i], bfr[j], acc[i][j], 0, 0, 0);
        }
        __syncthreads();
    };

    for (int t2 = 0; t2 < 6; ++t2) {             // K=768: 12 steps
        kstep(Ash[0], Bsh[0], Ash[1], Bsh[1], true);
        kstep(Ash[1], Bsh[1], Ash[0], Bsh[0], t2 < 5);
    }

    const int cc = lane & 15, g4 = (lane >> 4) * 4;
    #pragma unroll
    for (int j = 0; j < 2; ++j) {
        int col = n0 + wc + j * 16 + cc;
        float bv = bias[col];
        #pragma unroll
        for (int i = 0; i < 2; ++i) {
            #pragma unroll
            for (int r = 0; r < 4; ++r) {
                int row = m0 + wr + i * 16 + g4 + r;
                Cout[(size_t)row * N + col] = acc[i][j][r] + bv;
            }
        }
    }
}

// ---------------- flash attention: 2x2 wave split (q-half x kv-half), shift-0 softmax ----------------
// Round-9..14 verified kernel; ONLY change this round: QK^T C-operand zero-init flows
// through a persistent z0 quad (deletes ~16 v_mov/tile). No extra MFMAs; l stays f32
// (round-10's ones-MFMA regression is NOT repeated).
__global__ __launch_bounds__(256) void attn_fwd(const unsigned short* __restrict__ qkv,
                                                const unsigned short* __restrict__ vt,
                                                unsigned short* __restrict__ ao) {
    __shared__ __align__(16) char smem[40960];
    unsigned short* Qs  = (unsigned short*)smem;              // [64*64] 8 KB
    unsigned short* Ks0 = (unsigned short*)(smem + 8192);
    unsigned short* Ks1 = (unsigned short*)(smem + 16384);
    unsigned short* Vs0 = (unsigned short*)(smem + 24576);
    unsigned short* Vs1 = (unsigned short*)(smem + 32768);
    float* Of    = (float*)smem;            // epilogue overlay: [64 q][68] f32 = 17408 B
    float* l_lds = (float*)(smem + 17408);  // [64] f32 (both overlay dead K/Q buffers)

    const int h = blockIdx.y, q0 = blockIdx.x * 64;
    const int tid = threadIdx.x, wid = tid >> 6, lane = tid & 63;
    const int g = lane >> 4, qc = lane & 15, x = qc & 7;
    const int wq = wid >> 1, wk = wid & 1;

    const unsigned short* qg_ = qkv + (size_t)q0 * 2304 + h * 64;
    const unsigned short* kgb = qkv + 768 + h * 64;
    const unsigned short* vgb = vt + (size_t)h * 64 * 4096;

    #pragma unroll
    for (int gg = 0; gg < 2; ++gg) {
        int rt = (wid * 2 + gg) * 8;
        stage_rows8(qg_ + (size_t)rt * 2304, 2304, Qs + rt * 64, lane);
        stage_rows8(kgb + (size_t)rt * 2304, 2304, Ks0 + rt * 64, lane);
        stage_rows8(vgb + (size_t)rt * 4096, 4096, Vs0 + rt * 64, lane);
    }
    __syncthreads();

    bh8 qf[2][2];
    #pragma unroll
    for (int qg = 0; qg < 2; ++qg)
        #pragma unroll
        for (int kc = 0; kc < 2; ++kc)
            qf[qg][kc] = frag_ld(Qs, 32 * wq + 16 * qg + qc, 4 * kc, lane);

    int koff[2][2], voff[4];
    #pragma unroll
    for (int jm = 0; jm < 2; ++jm)
        #pragma unroll
        for (int kc = 0; kc < 2; ++kc)
            koff[jm][kc] = (32 * wk + 16 * jm + qc) * 64 + ((4 * kc + g) ^ x) * 8;
    #pragma unroll
    for (int dj = 0; dj < 4; ++dj)
        voff[dj] = (16 * dj + qc) * 64 + ((4 * wk + g) ^ x) * 8;

    const fx4 z0 = (fx4){0.f, 0.f, 0.f, 0.f};
    f32x2 l2[2] = {(f32x2){0.f, 0.f}, (f32x2){0.f, 0.f}};
    fx4 oacP[4][2];
    #pragma unroll
    for (int dj = 0; dj < 4; ++dj)
        #pragma unroll
        for (int qg = 0; qg < 2; ++qg)
            oacP[dj][qg] = z0;

    const unsigned short* knext = kgb + (size_t)64 * 2304;
    const unsigned short* vnext = vgb + 64;

    auto tile_step = [&](const unsigned short* Kc, const unsigned short* Vc,
                         unsigned short* Kd, unsigned short* Vd, bool pref) {
        if (pref) {
            #pragma unroll
            for (int gg = 0; gg < 2; ++gg) {
                int rt = (wid * 2 + gg) * 8;
                stage_rows8(knext + (size_t)rt * 2304, 2304, Kd + rt * 64, lane);
                stage_rows8(vnext + (size_t)rt * 4096, 4096, Vd + rt * 64, lane);
            }
            knext += (size_t)64 * 2304;
            vnext += 64;
        }

        bh8 kf[2][2];
        #pragma unroll
        for (int jm = 0; jm < 2; ++jm) {
            kf[jm][0] = *(const bh8*)(Kc + koff[jm][0]);
            kf[jm][1] = *(const bh8*)(Kc + koff[jm][1]);
        }
        fx4 sT[2][2];
        __builtin_amdgcn_s_setprio(1);
        #pragma unroll
        for (int jm = 0; jm < 2; ++jm)
            #pragma unroll
            for (int qg = 0; qg < 2; ++qg) {
                fx4 z = __builtin_amdgcn_mfma_f32_16x16x32_bf16(kf[jm][0], qf[qg][0], z0, 0, 0, 0);
                sT[jm][qg] = __builtin_amdgcn_mfma_f32_16x16x32_bf16(kf[jm][1], qf[qg][1], z, 0, 0, 0);
            }
        __builtin_amdgcn_s_setprio(0);

        #pragma unroll
        for (int jm = 0; jm < 2; ++jm)
            #pragma unroll
            for (int qg = 0; qg < 2; ++qg) {
                sT[jm][qg][0] = __builtin_amdgcn_exp2f(sT[jm][qg][0]);
                sT[jm][qg][1] = __builtin_amdgcn_exp2f(sT[jm][qg][1]);
                sT[jm][qg][2] = __builtin_amdgcn_exp2f(sT[jm][qg][2]);
                sT[jm][qg][3] = __builtin_amdgcn_exp2f(sT[jm][qg][3]);
                l2[qg] += __builtin_shufflevector(sT[jm][qg], sT[jm][qg], 0, 1)
                        + __builtin_shufflevector(sT[jm][qg], sT[jm][qg], 2, 3);
            }

        bh8 vf[4];
        #pragma unroll
        for (int dj = 0; dj < 4; ++dj) vf[dj] = *(const bh8*)(Vc + voff[dj]);
        __builtin_amdgcn_s_setprio(1);
        #pragma unroll
        for (int qg = 0; qg < 2; ++qg) {
            bh8 pb = pack4(cvtpk_bf16(sT[0][qg][0], sT[0][qg][1]),
                           cvtpk_bf16(sT[0][qg][2], sT[0][qg][3]),
                           cvtpk_bf16(sT[1][qg][0], sT[1][qg][1]),
                           cvtpk_bf16(sT[1][qg][2], sT[1][qg][3]));
            #pragma unroll
            for (int dj = 0; dj < 4; ++dj)
                oacP[dj][qg] = __builtin_amdgcn_mfma_f32_16x16x32_bf16(vf[dj], pb, oacP[dj][qg], 0, 0, 0);
        }
        __builtin_amdgcn_s_setprio(0);
        __syncthreads();
    };

    for (int t2 = 0; t2 < 32; ++t2) {
        tile_step(Ks0, Vs0, Ks1, Vs1, true);
        tile_step(Ks1, Vs1, Ks0, Vs0, t2 < 31);
    }

    float lrun[2];
    #pragma unroll
    for (int qg = 0; qg < 2; ++qg) {
        lrun[qg] = l2[qg][0] + l2[qg][1];
        lrun[qg] += __shfl_xor(lrun[qg], 16);
        lrun[qg] += __shfl_xor(lrun[qg], 32);
    }
    if (wk == 1) {
        #pragma unroll
        for (int qg = 0; qg < 2; ++qg) {
            int q = 32 * wq + 16 * qg + qc;
            #pragma unroll
            for (int dj = 0; dj < 4; ++dj)
                *(fx4*)(Of + q * 68 + 16 * dj + 4 * g) = oacP[dj][qg];
            l_lds[q] = lrun[qg];
        }
    }
    __syncthreads();
    if (wk == 0) {
        #pragma unroll
        for (int qg = 0; qg < 2; ++qg) {
            int q = 32 * wq + 16 * qg + qc;
            float inv = 1.0f / (lrun[qg] + l_lds[q]);
            unsigned short* aop = ao + (size_t)(q0 + q) * 768 + h * 64;
            #pragma unroll
            for (int dj = 0; dj < 4; ++dj) {
                fx4 o = oacP[dj][qg];
                fx4 p = *(const fx4*)(Of + q * 68 + 16 * dj + 4 * g);
                int d0 = dj * 16 + 4 * g;
                *(unsigned int*)(aop + d0)     = cvtpk_bf16((o[0] + p[0]) * inv, (o[1] + p[1]) * inv);
                *(unsigned int*)(aop + d0 + 2) = cvtpk_bf16((o[2] + p[2]) * inv, (o[3] + p[3]) * inv);
            }
        }
    }
}

extern "C" void kernel_launch(void* const* d_in, const int* in_sizes, int n_in,
                              void* d_out, int out_size, void* d_ws, size_t ws_size,
                              hipStream_t stream) {
    const float* x     = (const float*)d_in[0];   // [4096,768]
    const float* w_qkv = (const float*)d_in[1];   // [768,2304]
    const float* b_qkv = (const float*)d_in[2];   // [2304]
    const float* w_out = (const float*)d_in[3];   // [768,768]
    const float* b_out = (const float*)d_in[4];   // [768]
    float* out = (float*)d_out;                   // [4096,768] fp32

    const int S = 4096, E = 768, E3 = 2304, H = 12;

    unsigned short* xb    = (unsigned short*)d_ws;          // S*E
    unsigned short* wqkvT = xb    + (size_t)S * E;          // E3*E
    unsigned short* woutT = wqkvT + (size_t)E3 * E;         // E*E
    unsigned short* qkvb  = woutT + (size_t)E * E;          // S*E3 (V third unused)
    unsigned short* vtp   = qkvb  + (size_t)S * E3;         // H*64*S
    unsigned short* ao    = vtp   + (size_t)H * 64 * S;     // S*E

    prep<<<dim3(3072 + 1728 + 576), 256, 0, stream>>>(x, xb, w_qkv, wqkvT, w_out, woutT);
    gemm_qkv<<<dim3(1152), 256, 0, stream>>>(xb, wqkvT, b_qkv, qkvb, vtp);
    attn_fwd<<<dim3(S / 64, H), 256, 0, stream>>>(qkvb, vtp, ao);
    gemm64<<<dim3(E / 64, S / 64), 256, 0, stream>>>(ao, woutT, b_out, out, S, E, E);
}